// Round 2
// baseline (3241.891 us; speedup 1.0000x reference)
//
#include <hip/hip_runtime.h>

#define T_ 3
#define NPER 20000
#define NN 60000
#define EE 480000
#define BB 200000
#define RR 5
#define NT 3130   // BB/64 + RR  (padded pair tiles)

__device__ inline float lrelu(float x){ return x > 0.f ? x : 0.2f*x; }
__device__ inline float eluf(float x){ return x > 0.f ? x : (__expf(x) - 1.f); }

// ---- input FC: nt[n,o] = feats[n,:] @ fc_w[t] + fc_b[t] ----
__global__ void k_input_fc(const float* __restrict__ feats, const float* __restrict__ fcw,
                           const float* __restrict__ fcb, float* __restrict__ nt) {
    int gid = blockIdx.x*256 + threadIdx.x;
    int n = gid >> 5, o = gid & 31;
    if (n >= NN) return;
    int t = n / NPER;
    const float* fr = feats + (size_t)n*64;
    const float* w = fcw + t*(64*32);
    float acc = fcb[t*32+o];
    #pragma unroll
    for (int k = 0; k < 64; ++k) acc += fr[k] * w[k*32+o];
    nt[n*32+o] = acc;
}

// ---- emb0: z[:,0:32] = nt/(3*||nt||) ----
__global__ void k_emb0(const float* __restrict__ nt, float* __restrict__ z) {
    int gid = blockIdx.x*256 + threadIdx.x;
    int n = gid >> 5, c = gid & 31;
    if (n >= NN) return;
    float v = nt[n*32+c];
    float ss = v*v;
    for (int off = 16; off; off >>= 1) ss += __shfl_xor(ss, off, 32);
    float nr = fmaxf(sqrtf(ss), 1e-12f);
    z[(size_t)n*128 + c] = v / (3.f*nr);
}

// ---- edge logit table [R,H] ----
__global__ void k_tab(const float* __restrict__ eemb, const float* __restrict__ fcw,
                      const float* __restrict__ fcb, const float* __restrict__ ae,
                      int H, float* __restrict__ tab) {
    int r = blockIdx.x / H, h = blockIdx.x % H, d = threadIdx.x;
    float acc = fcb[h*64+d];
    const float* er = eemb + r*64;
    #pragma unroll
    for (int k = 0; k < 64; ++k) acc += er[k] * fcw[k*(H*64) + h*64 + d];
    float v = acc * ae[h*64+d];
    for (int off = 32; off; off >>= 1) v += __shfl_xor(v, off, 64);
    if (d == 0) tab[r*H+h] = v;
}

// ---- layer0 f (compact [N,64]) + el/er ----
__global__ void k_f0(const float* __restrict__ nt, const float* __restrict__ w0,
                     const float* __restrict__ al, const float* __restrict__ ar,
                     float* __restrict__ f0, float* __restrict__ el, float* __restrict__ er) {
    int gid = blockIdx.x*256 + threadIdx.x;
    int n = gid >> 6, l = gid & 63;
    if (n >= NN) return;
    int t = n / NPER, h = l >> 5, d = l & 31;
    const float* ntp = nt + n*32;
    const float* wp = w0 + t*(32*64);
    float acc = 0.f;
    #pragma unroll
    for (int i = 0; i < 32; ++i) acc += ntp[i] * wp[i*64 + l];
    f0[(size_t)n*64+l] = acc;
    float pe = acc * al[h*96 + t*32 + d];
    float pr = acc * ar[h*96 + t*32 + d];
    for (int off = 16; off; off >>= 1) { pe += __shfl_xor(pe, off, 32); pr += __shfl_xor(pr, off, 32); }
    if (d == 0) { el[n*2+h] = pe; er[n*2+h] = pr; }
}

// ---- CSR build ----
__global__ void k_deg(const int* __restrict__ dst, int* __restrict__ deg) {
    int e = blockIdx.x*256 + threadIdx.x;
    if (e < EE) atomicAdd(&deg[dst[e]], 1);
}

__global__ __launch_bounds__(1024) void k_scan(const int* __restrict__ deg, int* __restrict__ rowptr) {
    __shared__ int sbase;
    __shared__ int wsum[16];
    int tid = threadIdx.x;
    if (tid == 0) sbase = 0;
    __syncthreads();
    for (int c0 = 0; c0 < NN; c0 += 1024) {
        int i = c0 + tid;
        int v = (i < NN) ? deg[i] : 0;
        int x = v;
        for (int d = 1; d < 64; d <<= 1) { int y = __shfl_up(x, d, 64); if ((tid & 63) >= d) x += y; }
        if ((tid & 63) == 63) wsum[tid >> 6] = x;
        __syncthreads();
        if (tid < 16) { int w = wsum[tid];
            for (int d = 1; d < 16; d <<= 1) { int y = __shfl_up(w, d, 64); if (tid >= d) w += y; }
            wsum[tid] = w; }
        __syncthreads();
        int woff = (tid >> 6) == 0 ? 0 : wsum[(tid >> 6) - 1];
        int incl = x + woff;
        if (i < NN) rowptr[i] = sbase + incl - v;
        __syncthreads();
        if (tid == 1023) sbase += incl;
        __syncthreads();
    }
    if (tid == 0) rowptr[NN] = sbase;
}

__global__ void k_fill(const int* __restrict__ dst, const int* __restrict__ rowptr,
                       int* __restrict__ cursor, int* __restrict__ eidx) {
    int e = blockIdx.x*256 + threadIdx.x;
    if (e >= EE) return;
    int d = dst[e];
    int pos = atomicAdd(&cursor[d], 1);
    eidx[rowptr[d] + pos] = e;
}

// ---- pair bucketing by relation ----
__global__ void k_bcnt(const int* __restrict__ mid, int* __restrict__ cnt) {
    int b = blockIdx.x*256 + threadIdx.x;
    if (b < BB) atomicAdd(&cnt[mid[b]], 1);
}
__global__ void k_bscan(const int* __restrict__ cnt, int* __restrict__ base) {
    base[0] = 0;
    for (int r = 0; r < RR; ++r) base[r+1] = base[r] + (((cnt[r] + 63) >> 6) << 6);
}
__global__ void k_bfill(const int* __restrict__ mid, const int* __restrict__ base,
                        int* __restrict__ cur, int* __restrict__ perm) {
    int b = blockIdx.x*256 + threadIdx.x;
    if (b >= BB) return;
    int r = mid[b];
    int pos = atomicAdd(&cur[r], 1);
    perm[base[r] + pos] = b;
}

// ---- fused per-node softmax + gather-aggregate ----
// MODE 0: H=2, f=[N,64] slot-compact, store a->store0, out=acc
// MODE 1: H=2, f=[N,192], mix resat, out=resid+acc
// MODE 2: H=1, f=[N,96], out(96)=resid+acc (in place)
template<int MODE, int H>
__global__ __launch_bounds__(192) void k_aggr(
        const int* __restrict__ rowptr, const int* __restrict__ eidx,
        const int* __restrict__ src, const int* __restrict__ et,
        const float* __restrict__ el, const float* __restrict__ er,
        const float* __restrict__ tab, const float* __restrict__ f,
        const float* __restrict__ resat, float* __restrict__ store0,
        const float* __restrict__ resid, float* __restrict__ outp) {
    __shared__ float s_a[128][2];
    __shared__ int s_src[128];
    __shared__ int s_ts[128];
    int n = blockIdx.x, tid = threadIdx.x;
    int e0 = rowptr[n];
    int deg = rowptr[n+1] - e0;
    float m0 = -1e30f, m1 = -1e30f, sum0 = 0.f, sum1 = 0.f;
    float er0 = 0.f, er1 = 0.f;
    if (tid < 64) {
        er0 = er[n*H];
        if (H == 2) er1 = er[n*H+1];
        for (int s2 = tid; s2 < deg; s2 += 64) {
            int e = eidx[e0+s2]; int sN = src[e]; int rr = et[e];
            float x0 = lrelu(el[sN*H] + er0 + tab[rr*H]);
            m0 = fmaxf(m0, x0);
            if (H == 2) { float x1 = lrelu(el[sN*H+1] + er1 + tab[rr*H+1]); m1 = fmaxf(m1, x1); }
        }
        for (int off = 32; off; off >>= 1) {
            m0 = fmaxf(m0, __shfl_xor(m0, off, 64));
            if (H == 2) m1 = fmaxf(m1, __shfl_xor(m1, off, 64));
        }
        for (int s2 = tid; s2 < deg; s2 += 64) {
            int e = eidx[e0+s2]; int sN = src[e]; int rr = et[e];
            float x0 = lrelu(el[sN*H] + er0 + tab[rr*H]);
            sum0 += __expf(x0 - m0);
            if (H == 2) { float x1 = lrelu(el[sN*H+1] + er1 + tab[rr*H+1]); sum1 += __expf(x1 - m1); }
        }
        for (int off = 32; off; off >>= 1) {
            sum0 += __shfl_xor(sum0, off, 64);
            if (H == 2) sum1 += __shfl_xor(sum1, off, 64);
        }
    }
    float acc = 0.f;
    int h = tid / 96, km = tid - h*96, t = km >> 5, d = km & 31;
    for (int c0 = 0; c0 < deg; c0 += 128) {
        int cl = min(128, deg - c0);
        if (tid < 64) {
            for (int s2 = tid; s2 < cl; s2 += 64) {
                int e = eidx[e0+c0+s2]; int sN = src[e]; int rr = et[e];
                float x0 = lrelu(el[sN*H] + er0 + tab[rr*H]);
                float a0 = __expf(x0 - m0) / (sum0 + 1e-9f);
                if (MODE == 1) a0 = a0*0.95f + resat[e*2]*0.05f;
                if (MODE == 0) store0[e*2] = a0;
                s_a[s2][0] = a0;
                if (H == 2) {
                    float x1 = lrelu(el[sN*H+1] + er1 + tab[rr*H+1]);
                    float a1 = __expf(x1 - m1) / (sum1 + 1e-9f);
                    if (MODE == 1) a1 = a1*0.95f + resat[e*2+1]*0.05f;
                    if (MODE == 0) store0[e*2+1] = a1;
                    s_a[s2][1] = a1;
                }
                s_src[s2] = sN;
                if (MODE == 0) s_ts[s2] = sN / NPER;
            }
        }
        __syncthreads();
        if (MODE == 0) {
            for (int s2 = 0; s2 < cl; ++s2)
                if (s_ts[s2] == t) acc += s_a[s2][h] * f[(size_t)s_src[s2]*64 + h*32 + d];
        } else if (MODE == 1) {
            for (int s2 = 0; s2 < cl; ++s2)
                acc += s_a[s2][h] * f[(size_t)s_src[s2]*192 + tid];
        } else {
            if (tid < 96)
                for (int s2 = 0; s2 < cl; ++s2)
                    acc += s_a[s2][0] * f[(size_t)s_src[s2]*96 + tid];
        }
        __syncthreads();
    }
    if (MODE == 0) outp[(size_t)n*192 + tid] = acc;
    else if (MODE == 1) outp[(size_t)n*192 + tid] = resid[(size_t)n*192 + tid] + acc;
    else if (tid < 96) outp[(size_t)n*96 + tid] = resid[(size_t)n*96 + tid] + acc;
}

// ---- layer1 feat ----
__global__ __launch_bounds__(192) void k_f1(const float* __restrict__ h1, const float* __restrict__ w1,
                     float* __restrict__ f1) {
    __shared__ float hrow[192];
    int n = blockIdx.x, tid = threadIdx.x;
    hrow[tid] = h1[(size_t)n*192 + tid];
    __syncthreads();
    int h = tid / 96, km = tid - h*96, t = km >> 5, d = km & 31, o = h*32 + d;
    const float* wp = w1 + t*(64*64);
    float acc = 0.f;
    #pragma unroll
    for (int i = 0; i < 64; ++i) acc += hrow[(i>>5)*96 + t*32 + (i&31)] * wp[i*64+o];
    f1[(size_t)n*192 + tid] = acc;
}

// ---- el/er for layer1 ----
__global__ void k_el1(const float* __restrict__ f1, const float* __restrict__ al,
                      const float* __restrict__ ar, float* __restrict__ el, float* __restrict__ er) {
    int gid = blockIdx.x*256 + threadIdx.x;
    int n = gid >> 6, l = gid & 63;
    if (n >= NN) return;
    const float* b = f1 + (size_t)n*192;
    float v0 = b[l], v1 = b[l+64], v2 = b[l+128];
    float pe0 = v0*al[l],     pr0 = v0*ar[l];
    float pe1 = v2*al[l+128], pr1 = v2*ar[l+128];
    float me = v1*al[l+64], mr = v1*ar[l+64];
    if (l < 32) { pe0 += me; pr0 += mr; } else { pe1 += me; pr1 += mr; }
    for (int off = 32; off; off >>= 1) {
        pe0 += __shfl_xor(pe0, off, 64); pr0 += __shfl_xor(pr0, off, 64);
        pe1 += __shfl_xor(pe1, off, 64); pr1 += __shfl_xor(pr1, off, 64);
    }
    if (l == 0) { el[n*2] = pe0; el[n*2+1] = pe1; er[n*2] = pr0; er[n*2+1] = pr1; }
}

// ---- layer2 feat + residual ----
__global__ __launch_bounds__(192) void k_f2res(const float* __restrict__ h2, const float* __restrict__ w2,
                        const float* __restrict__ rw, float* __restrict__ f2,
                        float* __restrict__ rst2) {
    __shared__ float hrow[384];
    int tid = threadIdx.x;
    int nb = blockIdx.x*2;
    for (int j = tid; j < 384; j += 192) hrow[j] = h2[(size_t)nb*192 + j];
    __syncthreads();
    int ln = tid / 96, km = tid - ln*96;
    int n = nb + ln;
    int t = km >> 5, d = km & 31;
    const float* hr = hrow + ln*192;
    float accf = 0.f, accr = 0.f;
    #pragma unroll
    for (int i = 0; i < 64; ++i) {
        float hv = hr[(i>>5)*96 + t*32 + (i&31)];
        accf += hv * w2[t*2048 + i*32 + d];
        accr += hv * rw[i*32 + d];
    }
    f2[(size_t)n*96+km] = accf;
    rst2[(size_t)n*96+km] = accr;
}

// ---- el/er for layer2 ----
__global__ void k_el2(const float* __restrict__ f2, const float* __restrict__ al,
                      const float* __restrict__ ar, float* __restrict__ el, float* __restrict__ er) {
    int gid = blockIdx.x*256 + threadIdx.x;
    int n = gid >> 6, l = gid & 63;
    if (n >= NN) return;
    const float* b = f2 + (size_t)n*96;
    float v0 = b[l];
    float pe = v0*al[l], pr = v0*ar[l];
    if (l < 32) { float v1 = b[64+l]; pe += v1*al[64+l]; pr += v1*ar[64+l]; }
    for (int off = 32; off; off >>= 1) { pe += __shfl_xor(pe, off, 64); pr += __shfl_xor(pr, off, 64); }
    if (l == 0) { el[n] = pe; er[n] = pr; }
}

// ---- finalize layer 0/1 ----
__global__ __launch_bounds__(192) void k_final01(float* __restrict__ rst, const float* __restrict__ bias,
                          float* __restrict__ z, int zcol) {
    __shared__ float xs[2][96];
    __shared__ float sn[2];
    int tid = threadIdx.x;
    int ln = tid / 96, k = tid - ln*96;
    int n = blockIdx.x*2 + ln;
    if (tid < 2) sn[tid] = 0.f;
    float v0 = eluf(rst[(size_t)n*192 + k]      + bias[k]);
    float v1 = eluf(rst[(size_t)n*192 + 96 + k] + bias[96+k]);
    rst[(size_t)n*192 + k] = v0;
    rst[(size_t)n*192 + 96 + k] = v1;
    float x = 0.5f*(v0+v1);
    xs[ln][k] = x;
    __syncthreads();
    atomicAdd(&sn[ln], x*x);
    __syncthreads();
    float nr = fmaxf(sqrtf(sn[ln]), 1e-12f);
    if (k < 32) z[(size_t)n*128 + zcol + k] = (xs[ln][k] + xs[ln][32+k] + xs[ln][64+k]) / (3.f*nr);
}

// ---- finalize layer 2 ----
__global__ __launch_bounds__(192) void k_final2(const float* __restrict__ rst2, const float* __restrict__ bias,
                         float* __restrict__ z) {
    __shared__ float xs[2][96];
    __shared__ float sn[2];
    int tid = threadIdx.x;
    int ln = tid / 96, k = tid - ln*96;
    int n = blockIdx.x*2 + ln;
    if (tid < 2) sn[tid] = 0.f;
    float x = rst2[(size_t)n*96 + k] + bias[k];
    xs[ln][k] = x;
    __syncthreads();
    atomicAdd(&sn[ln], x*x);
    __syncthreads();
    float nr = fmaxf(sqrtf(sn[ln]), 1e-12f);
    if (k < 32) z[(size_t)n*128 + 96 + k] = (xs[ln][k] + xs[ln][32+k] + xs[ln][64+k]) / (3.f*nr);
}

// ---- DistMult: bucketed pair tiles, register-tiled; 64 pairs/block ----
__global__ __launch_bounds__(256) void k_dm2(const float* __restrict__ z, const float* __restrict__ W,
                       const int* __restrict__ left, const int* __restrict__ right,
                       const int* __restrict__ mid, const int* __restrict__ perm,
                       float* __restrict__ out) {
    __shared__ float le_s[64][129];
    __shared__ float w_s[32][128];
    __shared__ int s_b[64], s_l[64], s_r[64];
    int tid = threadIdx.x;
    if (tid < 64) {
        int b = perm[blockIdx.x*64 + tid];
        s_b[tid] = b;
        s_l[tid] = (b >= 0) ? left[b]  : 0;
        s_r[tid] = (b >= 0) ? right[b] : 0;
    }
    __syncthreads();
    if (s_b[0] < 0) return;
    int r = mid[s_b[0]];
    for (int i = tid; i < 8192; i += 256) {
        int p = i >> 7, c = i & 127;
        le_s[p][c] = z[(size_t)s_l[p]*128 + c];
    }
    const float* Wp = W + (size_t)r*16384;
    int tx = tid & 15, ty = tid >> 4;
    float acc[4][8];
    #pragma unroll
    for (int pp = 0; pp < 4; ++pp)
        #pragma unroll
        for (int i2 = 0; i2 < 8; ++i2) acc[pp][i2] = 0.f;
    for (int k0 = 0; k0 < 128; k0 += 32) {
        __syncthreads();
        for (int i = tid; i < 4096; i += 256) {
            int kk = i >> 7, c = i & 127;
            w_s[kk][c] = Wp[(size_t)(k0+kk)*128 + c];
        }
        __syncthreads();
        #pragma unroll 4
        for (int kk = 0; kk < 32; ++kk) {
            float wv[8], lv[4];
            #pragma unroll
            for (int i2 = 0; i2 < 8; ++i2) wv[i2] = w_s[kk][tx + 16*i2];
            #pragma unroll
            for (int pp = 0; pp < 4; ++pp) lv[pp] = le_s[ty*4+pp][k0+kk];
            #pragma unroll
            for (int pp = 0; pp < 4; ++pp)
                #pragma unroll
                for (int i2 = 0; i2 < 8; ++i2) acc[pp][i2] += lv[pp]*wv[i2];
        }
    }
    #pragma unroll
    for (int pp = 0; pp < 4; ++pp) {
        int p = ty*4 + pp;
        const float* zr = z + (size_t)s_r[p]*128;
        float part = 0.f;
        #pragma unroll
        for (int i2 = 0; i2 < 8; ++i2) part += acc[pp][i2] * zr[tx + 16*i2];
        for (int off = 8; off; off >>= 1) part += __shfl_xor(part, off, 64);
        if (tx == 0 && s_b[p] >= 0) out[s_b[p]] = part;
    }
}

extern "C" void kernel_launch(void* const* d_in, const int* in_sizes, int n_in,
                              void* d_out, int out_size, void* d_ws, size_t ws_size,
                              hipStream_t stream) {
    const float* feats = (const float*)d_in[0];
    const float* fc_w  = (const float*)d_in[1];
    const float* fc_b  = (const float*)d_in[2];
    const float* w0    = (const float*)d_in[3];
    const float* al0   = (const float*)d_in[4];
    const float* ar0   = (const float*)d_in[5];
    const float* b0    = (const float*)d_in[6];
    const float* eemb0 = (const float*)d_in[7];
    const float* fce_w0= (const float*)d_in[8];
    const float* fce_b0= (const float*)d_in[9];
    const float* ae0   = (const float*)d_in[10];
    const float* w1    = (const float*)d_in[11];
    const float* al1   = (const float*)d_in[12];
    const float* ar1   = (const float*)d_in[13];
    const float* b1    = (const float*)d_in[14];
    const float* eemb1 = (const float*)d_in[15];
    const float* fce_w1= (const float*)d_in[16];
    const float* fce_b1= (const float*)d_in[17];
    const float* ae1   = (const float*)d_in[18];
    const float* w2    = (const float*)d_in[19];
    const float* al2   = (const float*)d_in[20];
    const float* ar2   = (const float*)d_in[21];
    const float* b2    = (const float*)d_in[22];
    const float* eemb2 = (const float*)d_in[23];
    const float* fce_w2= (const float*)d_in[24];
    const float* fce_b2= (const float*)d_in[25];
    const float* ae2   = (const float*)d_in[26];
    const float* resw2 = (const float*)d_in[27];
    const float* Wdm   = (const float*)d_in[28];
    const int* src   = (const int*)d_in[29];
    const int* dst   = (const int*)d_in[30];
    const int* etype = (const int*)d_in[31];
    const int* left  = (const int*)d_in[32];
    const int* right = (const int*)d_in[33];
    const int* mid   = (const int*)d_in[34];
    float* out = (float*)d_out;

    char* ws = (char*)d_ws;
    size_t off = 0;
    auto alloc = [&](size_t bytes) -> void* {
        void* p = ws + off;
        off = (off + bytes + 255) & ~(size_t)255;
        return p;
    };
    float* nt   = (float*)alloc((size_t)NN*32*4);
    float* z    = (float*)alloc((size_t)NN*128*4);
    float* fbuf = (float*)alloc((size_t)NN*192*4);
    float* r0   = (float*)alloc((size_t)NN*192*4);
    float* r1   = (float*)alloc((size_t)NN*192*4);
    float* r2   = (float*)alloc((size_t)NN*96*4);
    float* el   = (float*)alloc((size_t)NN*2*4);
    float* er   = (float*)alloc((size_t)NN*2*4);
    float* a0b  = (float*)alloc((size_t)EE*2*4);
    int* rowptr = (int*)alloc((size_t)(NN+1)*4);
    int* eidx   = (int*)alloc((size_t)EE*4);
    int* degc   = (int*)alloc((size_t)NN*4);      // degree, then cursor
    int* perm   = (int*)alloc((size_t)NT*64*4);
    int* bcnt   = (int*)alloc(8*4);
    int* bbase  = (int*)alloc(8*4);
    int* bcur   = (int*)alloc(8*4);
    float* tab0 = (float*)alloc(256);
    float* tab1 = (float*)alloc(256);
    float* tab2 = (float*)alloc(256);

    // ---- CSR build (by dst) ----
    hipMemsetAsync(degc, 0, (size_t)NN*4, stream);
    k_deg<<<dim3(EE/256), dim3(256), 0, stream>>>(dst, degc);
    k_scan<<<dim3(1), dim3(1024), 0, stream>>>(degc, rowptr);
    hipMemsetAsync(degc, 0, (size_t)NN*4, stream);
    k_fill<<<dim3(EE/256), dim3(256), 0, stream>>>(dst, rowptr, degc, eidx);

    // ---- pair buckets by relation ----
    hipMemsetAsync(bcnt, 0, 8*4, stream);
    hipMemsetAsync(bcur, 0, 8*4, stream);
    hipMemsetAsync(perm, 0xFF, (size_t)NT*64*4, stream);
    k_bcnt<<<dim3((BB+255)/256), dim3(256), 0, stream>>>(mid, bcnt);
    k_bscan<<<dim3(1), dim3(1), 0, stream>>>(bcnt, bbase);
    k_bfill<<<dim3((BB+255)/256), dim3(256), 0, stream>>>(mid, bbase, bcur, perm);

    // ---- stage 0 ----
    k_input_fc<<<dim3((NN*32)/256), dim3(256), 0, stream>>>(feats, fc_w, fc_b, nt);
    k_emb0<<<dim3((NN*32)/256), dim3(256), 0, stream>>>(nt, z);
    k_tab<<<dim3(RR*2), dim3(64), 0, stream>>>(eemb0, fce_w0, fce_b0, ae0, 2, tab0);
    k_tab<<<dim3(RR*2), dim3(64), 0, stream>>>(eemb1, fce_w1, fce_b1, ae1, 2, tab1);
    k_tab<<<dim3(RR*1), dim3(64), 0, stream>>>(eemb2, fce_w2, fce_b2, ae2, 1, tab2);

    // ---- layer 0 ----
    k_f0<<<dim3((NN*64)/256), dim3(256), 0, stream>>>(nt, w0, al0, ar0, fbuf, el, er);
    k_aggr<0,2><<<dim3(NN), dim3(192), 0, stream>>>(rowptr, eidx, src, etype, el, er, tab0,
                                                    fbuf, nullptr, a0b, nullptr, r0);
    k_final01<<<dim3(NN/2), dim3(192), 0, stream>>>(r0, b0, z, 32);   // r0 -> h1

    // ---- layer 1 ----
    k_f1<<<dim3(NN), dim3(192), 0, stream>>>(r0, w1, fbuf);
    k_el1<<<dim3((NN*64)/256), dim3(256), 0, stream>>>(fbuf, al1, ar1, el, er);
    k_aggr<1,2><<<dim3(NN), dim3(192), 0, stream>>>(rowptr, eidx, src, etype, el, er, tab1,
                                                    fbuf, a0b, nullptr, r0, r1);
    k_final01<<<dim3(NN/2), dim3(192), 0, stream>>>(r1, b1, z, 64);   // r1 -> h2

    // ---- layer 2 ----
    k_f2res<<<dim3(NN/2), dim3(192), 0, stream>>>(r1, w2, resw2, fbuf, r2);
    k_el2<<<dim3((NN*64)/256), dim3(256), 0, stream>>>(fbuf, al2, ar2, el, er);
    k_aggr<2,1><<<dim3(NN), dim3(192), 0, stream>>>(rowptr, eidx, src, etype, el, er, tab2,
                                                    fbuf, nullptr, nullptr, r2, r2);
    k_final2<<<dim3(NN/2), dim3(192), 0, stream>>>(r2, b2, z);

    // ---- DistMult ----
    k_dm2<<<dim3(NT), dim3(256), 0, stream>>>(z, Wdm, left, right, mid, perm, out);
}

// Round 3
// 1327.095 us; speedup vs baseline: 2.4428x; 2.4428x over previous
//
#include <hip/hip_runtime.h>

#define T_ 3
#define NPER 20000
#define NN 60000
#define EE 480000
#define BB 200000
#define RR 5
#define NT 3130   // BB/64 + RR  (padded pair tiles)

__device__ inline float lrelu(float x){ return x > 0.f ? x : 0.2f*x; }
__device__ inline float eluf(float x){ return x > 0.f ? x : (__expf(x) - 1.f); }

// ---- input FC: nt[n,o] = feats[n,:] @ fc_w[t] + fc_b[t] ----
__global__ void k_input_fc(const float* __restrict__ feats, const float* __restrict__ fcw,
                           const float* __restrict__ fcb, float* __restrict__ nt) {
    int gid = blockIdx.x*256 + threadIdx.x;
    int n = gid >> 5, o = gid & 31;
    if (n >= NN) return;
    int t = n / NPER;
    const float* fr = feats + (size_t)n*64;
    const float* w = fcw + t*(64*32);
    float acc = fcb[t*32+o];
    #pragma unroll
    for (int k = 0; k < 64; ++k) acc += fr[k] * w[k*32+o];
    nt[n*32+o] = acc;
}

// ---- emb0: z[:,0:32] = nt/(3*||nt||) ----
__global__ void k_emb0(const float* __restrict__ nt, float* __restrict__ z) {
    int gid = blockIdx.x*256 + threadIdx.x;
    int n = gid >> 5, c = gid & 31;
    if (n >= NN) return;
    float v = nt[n*32+c];
    float ss = v*v;
    for (int off = 16; off; off >>= 1) ss += __shfl_xor(ss, off, 32);
    float nr = fmaxf(sqrtf(ss), 1e-12f);
    z[(size_t)n*128 + c] = v / (3.f*nr);
}

// ---- edge logit table [R,H] ----
__global__ void k_tab(const float* __restrict__ eemb, const float* __restrict__ fcw,
                      const float* __restrict__ fcb, const float* __restrict__ ae,
                      int H, float* __restrict__ tab) {
    int r = blockIdx.x / H, h = blockIdx.x % H, d = threadIdx.x;
    float acc = fcb[h*64+d];
    const float* er = eemb + r*64;
    #pragma unroll
    for (int k = 0; k < 64; ++k) acc += er[k] * fcw[k*(H*64) + h*64 + d];
    float v = acc * ae[h*64+d];
    for (int off = 32; off; off >>= 1) v += __shfl_xor(v, off, 64);
    if (d == 0) tab[r*H+h] = v;
}

// ---- layer0 f (compact [N,64]) + el/er ----
__global__ void k_f0(const float* __restrict__ nt, const float* __restrict__ w0,
                     const float* __restrict__ al, const float* __restrict__ ar,
                     float* __restrict__ f0, float* __restrict__ el, float* __restrict__ er) {
    int gid = blockIdx.x*256 + threadIdx.x;
    int n = gid >> 6, l = gid & 63;
    if (n >= NN) return;
    int t = n / NPER, h = l >> 5, d = l & 31;
    const float* ntp = nt + n*32;
    const float* wp = w0 + t*(32*64);
    float acc = 0.f;
    #pragma unroll
    for (int i = 0; i < 32; ++i) acc += ntp[i] * wp[i*64 + l];
    f0[(size_t)n*64+l] = acc;
    float pe = acc * al[h*96 + t*32 + d];
    float pr = acc * ar[h*96 + t*32 + d];
    for (int off = 16; off; off >>= 1) { pe += __shfl_xor(pe, off, 32); pr += __shfl_xor(pr, off, 32); }
    if (d == 0) { el[n*2+h] = pe; er[n*2+h] = pr; }
}

// ---- CSR build ----
__global__ void k_deg(const int* __restrict__ dst, int* __restrict__ deg) {
    int e = blockIdx.x*256 + threadIdx.x;
    if (e < EE) atomicAdd(&deg[dst[e]], 1);
}

__global__ __launch_bounds__(1024) void k_scan(const int* __restrict__ deg, int* __restrict__ rowptr) {
    __shared__ int sbase;
    __shared__ int wsum[16];
    int tid = threadIdx.x;
    if (tid == 0) sbase = 0;
    __syncthreads();
    for (int c0 = 0; c0 < NN; c0 += 1024) {
        int i = c0 + tid;
        int v = (i < NN) ? deg[i] : 0;
        int x = v;
        for (int d = 1; d < 64; d <<= 1) { int y = __shfl_up(x, d, 64); if ((tid & 63) >= d) x += y; }
        if ((tid & 63) == 63) wsum[tid >> 6] = x;
        __syncthreads();
        if (tid < 16) { int w = wsum[tid];
            for (int d = 1; d < 16; d <<= 1) { int y = __shfl_up(w, d, 64); if (tid >= d) w += y; }
            wsum[tid] = w; }
        __syncthreads();
        int woff = (tid >> 6) == 0 ? 0 : wsum[(tid >> 6) - 1];
        int incl = x + woff;
        if (i < NN) rowptr[i] = sbase + incl - v;
        __syncthreads();
        if (tid == 1023) sbase += incl;
        __syncthreads();
    }
    if (tid == 0) rowptr[NN] = sbase;
}

__global__ void k_fill(const int* __restrict__ dst, const int* __restrict__ rowptr,
                       int* __restrict__ cursor, int* __restrict__ eidx) {
    int e = blockIdx.x*256 + threadIdx.x;
    if (e >= EE) return;
    int d = dst[e];
    int pos = atomicAdd(&cursor[d], 1);
    eidx[rowptr[d] + pos] = e;
}

// ---- pair bucketing by relation: wave-ballot aggregated (5 hot addresses!) ----
__global__ __launch_bounds__(256) void k_bcnt(const int* __restrict__ mid, int* __restrict__ cnt) {
    __shared__ int h[RR];
    int tid = threadIdx.x, lane = tid & 63;
    if (tid < RR) h[tid] = 0;
    __syncthreads();
    int b = blockIdx.x*256 + tid;
    int r = (b < BB) ? mid[b] : -1;
    #pragma unroll
    for (int rr = 0; rr < RR; ++rr) {
        unsigned long long m = __ballot(r == rr);
        if (lane == 0 && m) atomicAdd(&h[rr], (int)__popcll(m));
    }
    __syncthreads();
    if (tid < RR && h[tid]) atomicAdd(&cnt[tid], h[tid]);
}

__global__ void k_bscan(const int* __restrict__ cnt, int* __restrict__ base) {
    base[0] = 0;
    for (int r = 0; r < RR; ++r) base[r+1] = base[r] + (((cnt[r] + 63) >> 6) << 6);
}

__global__ __launch_bounds__(256) void k_bfill(const int* __restrict__ mid, const int* __restrict__ base,
                        int* __restrict__ gcur, int* __restrict__ perm) {
    __shared__ int wcnt[4][RR];
    __shared__ int wbase[4][RR];
    __shared__ int bbase[RR];
    int tid = threadIdx.x, w = tid >> 6, lane = tid & 63;
    int b = blockIdx.x*256 + tid;
    int r = (b < BB) ? mid[b] : -1;
    int myrank = 0;
    #pragma unroll
    for (int rr = 0; rr < RR; ++rr) {
        unsigned long long m = __ballot(r == rr);
        if (r == rr) myrank = (int)__popcll(m & ((1ull << lane) - 1ull));
        if (lane == 0) wcnt[w][rr] = (int)__popcll(m);
    }
    __syncthreads();
    if (tid < RR) {
        int s = 0;
        #pragma unroll
        for (int ww = 0; ww < 4; ++ww) { wbase[ww][tid] = s; s += wcnt[ww][tid]; }
        bbase[tid] = s ? atomicAdd(&gcur[tid], s) : 0;
    }
    __syncthreads();
    if (r >= 0) perm[base[r] + bbase[r] + wbase[w][r] + myrank] = b;
}

// ---- fused per-node softmax + gather-aggregate ----
// MODE 0: H=2, f=[N,64] slot-compact, store a->store0, out=acc
// MODE 1: H=2, f=[N,192], mix resat, out=resid+acc
// MODE 2: H=1, f=[N,96], out(96)=resid+acc (in place)
template<int MODE, int H>
__global__ __launch_bounds__(192) void k_aggr(
        const int* __restrict__ rowptr, const int* __restrict__ eidx,
        const int* __restrict__ src, const int* __restrict__ et,
        const float* __restrict__ el, const float* __restrict__ er,
        const float* __restrict__ tab, const float* __restrict__ f,
        const float* __restrict__ resat, float* __restrict__ store0,
        const float* __restrict__ resid, float* __restrict__ outp) {
    __shared__ float s_a[128][2];
    __shared__ int s_src[128];
    __shared__ int s_ts[128];
    int n = blockIdx.x, tid = threadIdx.x;
    int e0 = rowptr[n];
    int deg = rowptr[n+1] - e0;
    float m0 = -1e30f, m1 = -1e30f, sum0 = 0.f, sum1 = 0.f;
    float er0 = 0.f, er1 = 0.f;
    if (tid < 64) {
        er0 = er[n*H];
        if (H == 2) er1 = er[n*H+1];
        for (int s2 = tid; s2 < deg; s2 += 64) {
            int e = eidx[e0+s2]; int sN = src[e]; int rr = et[e];
            float x0 = lrelu(el[sN*H] + er0 + tab[rr*H]);
            m0 = fmaxf(m0, x0);
            if (H == 2) { float x1 = lrelu(el[sN*H+1] + er1 + tab[rr*H+1]); m1 = fmaxf(m1, x1); }
        }
        for (int off = 32; off; off >>= 1) {
            m0 = fmaxf(m0, __shfl_xor(m0, off, 64));
            if (H == 2) m1 = fmaxf(m1, __shfl_xor(m1, off, 64));
        }
        for (int s2 = tid; s2 < deg; s2 += 64) {
            int e = eidx[e0+s2]; int sN = src[e]; int rr = et[e];
            float x0 = lrelu(el[sN*H] + er0 + tab[rr*H]);
            sum0 += __expf(x0 - m0);
            if (H == 2) { float x1 = lrelu(el[sN*H+1] + er1 + tab[rr*H+1]); sum1 += __expf(x1 - m1); }
        }
        for (int off = 32; off; off >>= 1) {
            sum0 += __shfl_xor(sum0, off, 64);
            if (H == 2) sum1 += __shfl_xor(sum1, off, 64);
        }
    }
    float acc = 0.f;
    int h = tid / 96, km = tid - h*96, t = km >> 5, d = km & 31;
    for (int c0 = 0; c0 < deg; c0 += 128) {
        int cl = min(128, deg - c0);
        if (tid < 64) {
            for (int s2 = tid; s2 < cl; s2 += 64) {
                int e = eidx[e0+c0+s2]; int sN = src[e]; int rr = et[e];
                float x0 = lrelu(el[sN*H] + er0 + tab[rr*H]);
                float a0 = __expf(x0 - m0) / (sum0 + 1e-9f);
                if (MODE == 1) a0 = a0*0.95f + resat[e*2]*0.05f;
                if (MODE == 0) store0[e*2] = a0;
                s_a[s2][0] = a0;
                if (H == 2) {
                    float x1 = lrelu(el[sN*H+1] + er1 + tab[rr*H+1]);
                    float a1 = __expf(x1 - m1) / (sum1 + 1e-9f);
                    if (MODE == 1) a1 = a1*0.95f + resat[e*2+1]*0.05f;
                    if (MODE == 0) store0[e*2+1] = a1;
                    s_a[s2][1] = a1;
                }
                s_src[s2] = sN;
                if (MODE == 0) s_ts[s2] = sN / NPER;
            }
        }
        __syncthreads();
        if (MODE == 0) {
            for (int s2 = 0; s2 < cl; ++s2)
                if (s_ts[s2] == t) acc += s_a[s2][h] * f[(size_t)s_src[s2]*64 + h*32 + d];
        } else if (MODE == 1) {
            for (int s2 = 0; s2 < cl; ++s2)
                acc += s_a[s2][h] * f[(size_t)s_src[s2]*192 + tid];
        } else {
            if (tid < 96)
                for (int s2 = 0; s2 < cl; ++s2)
                    acc += s_a[s2][0] * f[(size_t)s_src[s2]*96 + tid];
        }
        __syncthreads();
    }
    if (MODE == 0) outp[(size_t)n*192 + tid] = acc;
    else if (MODE == 1) outp[(size_t)n*192 + tid] = resid[(size_t)n*192 + tid] + acc;
    else if (tid < 96) outp[(size_t)n*96 + tid] = resid[(size_t)n*96 + tid] + acc;
}

// ---- layer1 feat ----
__global__ __launch_bounds__(192) void k_f1(const float* __restrict__ h1, const float* __restrict__ w1,
                     float* __restrict__ f1) {
    __shared__ float hrow[192];
    int n = blockIdx.x, tid = threadIdx.x;
    hrow[tid] = h1[(size_t)n*192 + tid];
    __syncthreads();
    int h = tid / 96, km = tid - h*96, t = km >> 5, d = km & 31, o = h*32 + d;
    const float* wp = w1 + t*(64*64);
    float acc = 0.f;
    #pragma unroll
    for (int i = 0; i < 64; ++i) acc += hrow[(i>>5)*96 + t*32 + (i&31)] * wp[i*64+o];
    f1[(size_t)n*192 + tid] = acc;
}

// ---- el/er for layer1 ----
__global__ void k_el1(const float* __restrict__ f1, const float* __restrict__ al,
                      const float* __restrict__ ar, float* __restrict__ el, float* __restrict__ er) {
    int gid = blockIdx.x*256 + threadIdx.x;
    int n = gid >> 6, l = gid & 63;
    if (n >= NN) return;
    const float* b = f1 + (size_t)n*192;
    float v0 = b[l], v1 = b[l+64], v2 = b[l+128];
    float pe0 = v0*al[l],     pr0 = v0*ar[l];
    float pe1 = v2*al[l+128], pr1 = v2*ar[l+128];
    float me = v1*al[l+64], mr = v1*ar[l+64];
    if (l < 32) { pe0 += me; pr0 += mr; } else { pe1 += me; pr1 += mr; }
    for (int off = 32; off; off >>= 1) {
        pe0 += __shfl_xor(pe0, off, 64); pr0 += __shfl_xor(pr0, off, 64);
        pe1 += __shfl_xor(pe1, off, 64); pr1 += __shfl_xor(pr1, off, 64);
    }
    if (l == 0) { el[n*2] = pe0; el[n*2+1] = pe1; er[n*2] = pr0; er[n*2+1] = pr1; }
}

// ---- layer2 feat + residual ----
__global__ __launch_bounds__(192) void k_f2res(const float* __restrict__ h2, const float* __restrict__ w2,
                        const float* __restrict__ rw, float* __restrict__ f2,
                        float* __restrict__ rst2) {
    __shared__ float hrow[384];
    int tid = threadIdx.x;
    int nb = blockIdx.x*2;
    for (int j = tid; j < 384; j += 192) hrow[j] = h2[(size_t)nb*192 + j];
    __syncthreads();
    int ln = tid / 96, km = tid - ln*96;
    int n = nb + ln;
    int t = km >> 5, d = km & 31;
    const float* hr = hrow + ln*192;
    float accf = 0.f, accr = 0.f;
    #pragma unroll
    for (int i = 0; i < 64; ++i) {
        float hv = hr[(i>>5)*96 + t*32 + (i&31)];
        accf += hv * w2[t*2048 + i*32 + d];
        accr += hv * rw[i*32 + d];
    }
    f2[(size_t)n*96+km] = accf;
    rst2[(size_t)n*96+km] = accr;
}

// ---- el/er for layer2 ----
__global__ void k_el2(const float* __restrict__ f2, const float* __restrict__ al,
                      const float* __restrict__ ar, float* __restrict__ el, float* __restrict__ er) {
    int gid = blockIdx.x*256 + threadIdx.x;
    int n = gid >> 6, l = gid & 63;
    if (n >= NN) return;
    const float* b = f2 + (size_t)n*96;
    float v0 = b[l];
    float pe = v0*al[l], pr = v0*ar[l];
    if (l < 32) { float v1 = b[64+l]; pe += v1*al[64+l]; pr += v1*ar[64+l]; }
    for (int off = 32; off; off >>= 1) { pe += __shfl_xor(pe, off, 64); pr += __shfl_xor(pr, off, 64); }
    if (l == 0) { el[n] = pe; er[n] = pr; }
}

// ---- finalize layer 0/1 ----
__global__ __launch_bounds__(192) void k_final01(float* __restrict__ rst, const float* __restrict__ bias,
                          float* __restrict__ z, int zcol) {
    __shared__ float xs[2][96];
    __shared__ float sn[2];
    int tid = threadIdx.x;
    int ln = tid / 96, k = tid - ln*96;
    int n = blockIdx.x*2 + ln;
    if (tid < 2) sn[tid] = 0.f;
    float v0 = eluf(rst[(size_t)n*192 + k]      + bias[k]);
    float v1 = eluf(rst[(size_t)n*192 + 96 + k] + bias[96+k]);
    rst[(size_t)n*192 + k] = v0;
    rst[(size_t)n*192 + 96 + k] = v1;
    float x = 0.5f*(v0+v1);
    xs[ln][k] = x;
    __syncthreads();
    atomicAdd(&sn[ln], x*x);
    __syncthreads();
    float nr = fmaxf(sqrtf(sn[ln]), 1e-12f);
    if (k < 32) z[(size_t)n*128 + zcol + k] = (xs[ln][k] + xs[ln][32+k] + xs[ln][64+k]) / (3.f*nr);
}

// ---- finalize layer 2 ----
__global__ __launch_bounds__(192) void k_final2(const float* __restrict__ rst2, const float* __restrict__ bias,
                         float* __restrict__ z) {
    __shared__ float xs[2][96];
    __shared__ float sn[2];
    int tid = threadIdx.x;
    int ln = tid / 96, k = tid - ln*96;
    int n = blockIdx.x*2 + ln;
    if (tid < 2) sn[tid] = 0.f;
    float x = rst2[(size_t)n*96 + k] + bias[k];
    xs[ln][k] = x;
    __syncthreads();
    atomicAdd(&sn[ln], x*x);
    __syncthreads();
    float nr = fmaxf(sqrtf(sn[ln]), 1e-12f);
    if (k < 32) z[(size_t)n*128 + 96 + k] = (xs[ln][k] + xs[ln][32+k] + xs[ln][64+k]) / (3.f*nr);
}

// ---- DistMult: bucketed pair tiles, register-tiled; 64 pairs/block ----
__global__ __launch_bounds__(256) void k_dm2(const float* __restrict__ z, const float* __restrict__ W,
                       const int* __restrict__ left, const int* __restrict__ right,
                       const int* __restrict__ mid, const int* __restrict__ perm,
                       float* __restrict__ out) {
    __shared__ float le_s[64][129];
    __shared__ float w_s[32][128];
    __shared__ int s_b[64], s_l[64], s_r[64];
    int tid = threadIdx.x;
    if (tid < 64) {
        int b = perm[blockIdx.x*64 + tid];
        s_b[tid] = b;
        s_l[tid] = (b >= 0) ? left[b]  : 0;
        s_r[tid] = (b >= 0) ? right[b] : 0;
    }
    __syncthreads();
    if (s_b[0] < 0) return;
    int r = mid[s_b[0]];
    for (int i = tid; i < 8192; i += 256) {
        int p = i >> 7, c = i & 127;
        le_s[p][c] = z[(size_t)s_l[p]*128 + c];
    }
    const float* Wp = W + (size_t)r*16384;
    int tx = tid & 15, ty = tid >> 4;
    float acc[4][8];
    #pragma unroll
    for (int pp = 0; pp < 4; ++pp)
        #pragma unroll
        for (int i2 = 0; i2 < 8; ++i2) acc[pp][i2] = 0.f;
    for (int k0 = 0; k0 < 128; k0 += 32) {
        __syncthreads();
        for (int i = tid; i < 4096; i += 256) {
            int kk = i >> 7, c = i & 127;
            w_s[kk][c] = Wp[(size_t)(k0+kk)*128 + c];
        }
        __syncthreads();
        #pragma unroll 4
        for (int kk = 0; kk < 32; ++kk) {
            float wv[8], lv[4];
            #pragma unroll
            for (int i2 = 0; i2 < 8; ++i2) wv[i2] = w_s[kk][tx + 16*i2];
            #pragma unroll
            for (int pp = 0; pp < 4; ++pp) lv[pp] = le_s[ty*4+pp][k0+kk];
            #pragma unroll
            for (int pp = 0; pp < 4; ++pp)
                #pragma unroll
                for (int i2 = 0; i2 < 8; ++i2) acc[pp][i2] += lv[pp]*wv[i2];
        }
    }
    #pragma unroll
    for (int pp = 0; pp < 4; ++pp) {
        int p = ty*4 + pp;
        const float* zr = z + (size_t)s_r[p]*128;
        float part = 0.f;
        #pragma unroll
        for (int i2 = 0; i2 < 8; ++i2) part += acc[pp][i2] * zr[tx + 16*i2];
        for (int off = 8; off; off >>= 1) part += __shfl_xor(part, off, 64);
        if (tx == 0 && s_b[p] >= 0) out[s_b[p]] = part;
    }
}

extern "C" void kernel_launch(void* const* d_in, const int* in_sizes, int n_in,
                              void* d_out, int out_size, void* d_ws, size_t ws_size,
                              hipStream_t stream) {
    const float* feats = (const float*)d_in[0];
    const float* fc_w  = (const float*)d_in[1];
    const float* fc_b  = (const float*)d_in[2];
    const float* w0    = (const float*)d_in[3];
    const float* al0   = (const float*)d_in[4];
    const float* ar0   = (const float*)d_in[5];
    const float* b0    = (const float*)d_in[6];
    const float* eemb0 = (const float*)d_in[7];
    const float* fce_w0= (const float*)d_in[8];
    const float* fce_b0= (const float*)d_in[9];
    const float* ae0   = (const float*)d_in[10];
    const float* w1    = (const float*)d_in[11];
    const float* al1   = (const float*)d_in[12];
    const float* ar1   = (const float*)d_in[13];
    const float* b1    = (const float*)d_in[14];
    const float* eemb1 = (const float*)d_in[15];
    const float* fce_w1= (const float*)d_in[16];
    const float* fce_b1= (const float*)d_in[17];
    const float* ae1   = (const float*)d_in[18];
    const float* w2    = (const float*)d_in[19];
    const float* al2   = (const float*)d_in[20];
    const float* ar2   = (const float*)d_in[21];
    const float* b2    = (const float*)d_in[22];
    const float* eemb2 = (const float*)d_in[23];
    const float* fce_w2= (const float*)d_in[24];
    const float* fce_b2= (const float*)d_in[25];
    const float* ae2   = (const float*)d_in[26];
    const float* resw2 = (const float*)d_in[27];
    const float* Wdm   = (const float*)d_in[28];
    const int* src   = (const int*)d_in[29];
    const int* dst   = (const int*)d_in[30];
    const int* etype = (const int*)d_in[31];
    const int* left  = (const int*)d_in[32];
    const int* right = (const int*)d_in[33];
    const int* mid   = (const int*)d_in[34];
    float* out = (float*)d_out;

    char* ws = (char*)d_ws;
    size_t off = 0;
    auto alloc = [&](size_t bytes) -> void* {
        void* p = ws + off;
        off = (off + bytes + 255) & ~(size_t)255;
        return p;
    };
    float* nt   = (float*)alloc((size_t)NN*32*4);
    float* z    = (float*)alloc((size_t)NN*128*4);
    float* fbuf = (float*)alloc((size_t)NN*192*4);
    float* r0   = (float*)alloc((size_t)NN*192*4);
    float* r1   = (float*)alloc((size_t)NN*192*4);
    float* r2   = (float*)alloc((size_t)NN*96*4);
    float* el   = (float*)alloc((size_t)NN*2*4);
    float* er   = (float*)alloc((size_t)NN*2*4);
    float* a0b  = (float*)alloc((size_t)EE*2*4);
    int* rowptr = (int*)alloc((size_t)(NN+1)*4);
    int* eidx   = (int*)alloc((size_t)EE*4);
    int* degc   = (int*)alloc((size_t)NN*4);      // degree, then cursor
    int* perm   = (int*)alloc((size_t)NT*64*4);
    int* bcnt   = (int*)alloc(8*4);
    int* bbase  = (int*)alloc(8*4);
    int* bcur   = (int*)alloc(8*4);
    float* tab0 = (float*)alloc(256);
    float* tab1 = (float*)alloc(256);
    float* tab2 = (float*)alloc(256);

    // ---- CSR build (by dst) ----
    hipMemsetAsync(degc, 0, (size_t)NN*4, stream);
    k_deg<<<dim3(EE/256), dim3(256), 0, stream>>>(dst, degc);
    k_scan<<<dim3(1), dim3(1024), 0, stream>>>(degc, rowptr);
    hipMemsetAsync(degc, 0, (size_t)NN*4, stream);
    k_fill<<<dim3(EE/256), dim3(256), 0, stream>>>(dst, rowptr, degc, eidx);

    // ---- pair buckets by relation ----
    hipMemsetAsync(bcnt, 0, 8*4, stream);
    hipMemsetAsync(bcur, 0, 8*4, stream);
    hipMemsetAsync(perm, 0xFF, (size_t)NT*64*4, stream);
    k_bcnt<<<dim3((BB+255)/256), dim3(256), 0, stream>>>(mid, bcnt);
    k_bscan<<<dim3(1), dim3(1), 0, stream>>>(bcnt, bbase);
    k_bfill<<<dim3((BB+255)/256), dim3(256), 0, stream>>>(mid, bbase, bcur, perm);

    // ---- stage 0 ----
    k_input_fc<<<dim3((NN*32)/256), dim3(256), 0, stream>>>(feats, fc_w, fc_b, nt);
    k_emb0<<<dim3((NN*32)/256), dim3(256), 0, stream>>>(nt, z);
    k_tab<<<dim3(RR*2), dim3(64), 0, stream>>>(eemb0, fce_w0, fce_b0, ae0, 2, tab0);
    k_tab<<<dim3(RR*2), dim3(64), 0, stream>>>(eemb1, fce_w1, fce_b1, ae1, 2, tab1);
    k_tab<<<dim3(RR*1), dim3(64), 0, stream>>>(eemb2, fce_w2, fce_b2, ae2, 1, tab2);

    // ---- layer 0 ----
    k_f0<<<dim3((NN*64)/256), dim3(256), 0, stream>>>(nt, w0, al0, ar0, fbuf, el, er);
    k_aggr<0,2><<<dim3(NN), dim3(192), 0, stream>>>(rowptr, eidx, src, etype, el, er, tab0,
                                                    fbuf, nullptr, a0b, nullptr, r0);
    k_final01<<<dim3(NN/2), dim3(192), 0, stream>>>(r0, b0, z, 32);   // r0 -> h1

    // ---- layer 1 ----
    k_f1<<<dim3(NN), dim3(192), 0, stream>>>(r0, w1, fbuf);
    k_el1<<<dim3((NN*64)/256), dim3(256), 0, stream>>>(fbuf, al1, ar1, el, er);
    k_aggr<1,2><<<dim3(NN), dim3(192), 0, stream>>>(rowptr, eidx, src, etype, el, er, tab1,
                                                    fbuf, a0b, nullptr, r0, r1);
    k_final01<<<dim3(NN/2), dim3(192), 0, stream>>>(r1, b1, z, 64);   // r1 -> h2

    // ---- layer 2 ----
    k_f2res<<<dim3(NN/2), dim3(192), 0, stream>>>(r1, w2, resw2, fbuf, r2);
    k_el2<<<dim3((NN*64)/256), dim3(256), 0, stream>>>(fbuf, al2, ar2, el, er);
    k_aggr<2,1><<<dim3(NN), dim3(192), 0, stream>>>(rowptr, eidx, src, etype, el, er, tab2,
                                                    fbuf, nullptr, nullptr, r2, r2);
    k_final2<<<dim3(NN/2), dim3(192), 0, stream>>>(r2, b2, z);

    // ---- DistMult ----
    k_dm2<<<dim3(NT), dim3(256), 0, stream>>>(z, Wdm, left, right, mid, perm, out);
}

// Round 4
// 1137.094 us; speedup vs baseline: 2.8510x; 1.1671x over previous
//
#include <hip/hip_runtime.h>

#define T_ 3
#define NPER 20000
#define NN 60000
#define EE 480000
#define BB 200000
#define RR 5
#define NT 3130    // BB/64 + RR  (padded pair tiles)
#define TILESN 938 // ceil(NN/64)
#define TILEST 313 // ceil(NPER/64)

__device__ inline float lrelu(float x){ return x > 0.f ? x : 0.2f*x; }
__device__ inline float eluf(float x){ return x > 0.f ? x : (__expf(x) - 1.f); }

// ---- combine input-fc with layer0 weights: cw[t]=fcw[t]@w0[t] [64x64], cb[t]=fcb[t]@w0[t] ----
__global__ __launch_bounds__(256) void k_combine(const float* __restrict__ fcw,
        const float* __restrict__ fcb, const float* __restrict__ w0,
        float* __restrict__ cw, float* __restrict__ cb) {
    __shared__ float A[64*32];   // fcw_t [k][m]
    __shared__ float Bm[32*64];  // w0_t  [m][o]
    int t = blockIdx.x, tid = threadIdx.x;
    for (int e = tid; e < 2048; e += 256) { A[e] = fcw[t*2048 + e]; Bm[e] = w0[t*2048 + e]; }
    __syncthreads();
    for (int e = tid; e < 4096; e += 256) {
        int k = e >> 6, o = e & 63;
        float acc = 0.f;
        #pragma unroll
        for (int m = 0; m < 32; ++m) acc += A[k*32+m] * Bm[m*64+o];
        cw[t*4096 + e] = acc;
    }
    if (tid < 64) {
        float acc = 0.f;
        #pragma unroll
        for (int m = 0; m < 32; ++m) acc += fcb[t*32+m] * Bm[m*64+tid];
        cb[t*64 + tid] = acc;
    }
}

// ---- fused input-fc + emb0: z[:,0:32] = (feats@fcw_t+fcb_t) / (3*||.||) ----
__global__ __launch_bounds__(256) void k_ntz(const float* __restrict__ feats,
        const float* __restrict__ fcw, const float* __restrict__ fcb,
        float* __restrict__ z) {
    __shared__ float Xs[64][65];
    __shared__ float Ws[64*32];
    __shared__ float nrS[64];
    int ty = blockIdx.y;
    int n0 = ty*NPER + blockIdx.x*64;
    int nmax = (ty+1)*NPER;
    int tid = threadIdx.x;
    for (int e = tid; e < 4096; e += 256) {
        int n = e >> 6, k = e & 63;
        int gn = n0 + n;
        Xs[n][k] = (gn < nmax) ? feats[(size_t)gn*64 + k] : 0.f;
    }
    for (int e = tid; e < 2048; e += 256) Ws[e] = fcw[ty*2048 + e];
    __syncthreads();
    int ix = tid & 15, iy = tid >> 4;  // nodes 4ix.., cols 2iy..
    float acc[4][2] = {};
    #pragma unroll 8
    for (int k = 0; k < 64; ++k) {
        float wa = Ws[k*32 + 2*iy], wb = Ws[k*32 + 2*iy + 1];
        #pragma unroll
        for (int p = 0; p < 4; ++p) {
            float x = Xs[ix*4+p][k];
            acc[p][0] += x*wa; acc[p][1] += x*wb;
        }
    }
    float ba = fcb[ty*32 + 2*iy], bb = fcb[ty*32 + 2*iy + 1];
    __syncthreads();
    #pragma unroll
    for (int p = 0; p < 4; ++p) {
        acc[p][0] += ba; acc[p][1] += bb;
        Xs[ix*4+p][2*iy] = acc[p][0]; Xs[ix*4+p][2*iy+1] = acc[p][1];
    }
    __syncthreads();
    if (tid < 64) {
        float ss = 0.f;
        #pragma unroll
        for (int c = 0; c < 32; ++c) { float v = Xs[tid][c]; ss += v*v; }
        nrS[tid] = 3.f * fmaxf(sqrtf(ss), 1e-12f);
    }
    __syncthreads();
    #pragma unroll
    for (int p = 0; p < 4; ++p) {
        int gn = n0 + ix*4 + p;
        if (gn < nmax) {
            float inv = 1.f / nrS[ix*4+p];
            z[(size_t)gn*128 + 2*iy]   = acc[p][0]*inv;
            z[(size_t)gn*128 + 2*iy+1] = acc[p][1]*inv;
        }
    }
}

// ---- layer0 feat (GEMM-tiled): f0 = feats@cw_t + cb_t, + el/er epilogue ----
__global__ __launch_bounds__(256) void k_f0t(const float* __restrict__ feats,
        const float* __restrict__ cw, const float* __restrict__ cb,
        const float* __restrict__ al, const float* __restrict__ ar,
        float* __restrict__ f0, float* __restrict__ el, float* __restrict__ er) {
    __shared__ float Xs[64][65];
    __shared__ float Ws[64*64];
    __shared__ float avec[2][32], rvec[2][32];
    int ty = blockIdx.y;
    int n0 = ty*NPER + blockIdx.x*64;
    int nmax = (ty+1)*NPER;
    int tid = threadIdx.x;
    for (int e = tid; e < 4096; e += 256) {
        int n = e >> 6, k = e & 63;
        int gn = n0 + n;
        Xs[n][k] = (gn < nmax) ? feats[(size_t)gn*64 + k] : 0.f;
        Ws[e] = cw[ty*4096 + e];
    }
    if (tid < 64) {
        avec[tid>>5][tid&31] = al[(tid>>5)*96 + ty*32 + (tid&31)];
        rvec[tid>>5][tid&31] = ar[(tid>>5)*96 + ty*32 + (tid&31)];
    }
    __syncthreads();
    int ix = tid & 15, iy = tid >> 4;  // nodes 4ix.., cols 4iy..
    float acc[4][4] = {};
    #pragma unroll 8
    for (int k = 0; k < 64; ++k) {
        float4 wv = *(const float4*)&Ws[k*64 + iy*4];
        #pragma unroll
        for (int p = 0; p < 4; ++p) {
            float x = Xs[ix*4+p][k];
            acc[p][0] += x*wv.x; acc[p][1] += x*wv.y; acc[p][2] += x*wv.z; acc[p][3] += x*wv.w;
        }
    }
    float b0v = cb[ty*64 + iy*4], b1v = cb[ty*64 + iy*4+1], b2v = cb[ty*64 + iy*4+2], b3v = cb[ty*64 + iy*4+3];
    __syncthreads();   // done with Xs; reuse as F tile
    #pragma unroll
    for (int p = 0; p < 4; ++p) {
        acc[p][0] += b0v; acc[p][1] += b1v; acc[p][2] += b2v; acc[p][3] += b3v;
        Xs[ix*4+p][iy*4]   = acc[p][0];
        Xs[ix*4+p][iy*4+1] = acc[p][1];
        Xs[ix*4+p][iy*4+2] = acc[p][2];
        Xs[ix*4+p][iy*4+3] = acc[p][3];
    }
    #pragma unroll
    for (int p = 0; p < 4; ++p) {
        int gn = n0 + ix*4 + p;
        if (gn < nmax)
            *(float4*)&f0[(size_t)gn*64 + iy*4] = make_float4(acc[p][0],acc[p][1],acc[p][2],acc[p][3]);
    }
    __syncthreads();
    if (tid < 128) {
        int n = tid >> 1, h = tid & 1;
        int gn = n0 + n;
        float pe = 0.f, pr = 0.f;
        #pragma unroll
        for (int d = 0; d < 32; ++d) {
            float v = Xs[n][h*32+d];
            pe += v*avec[h][d]; pr += v*rvec[h][d];
        }
        if (gn < nmax) { el[gn*2+h] = pe; er[gn*2+h] = pr; }
    }
}

// ---- layer1 feat (GEMM-tiled per slot t) ----
__global__ __launch_bounds__(256) void k_f1t(const float* __restrict__ h1,
        const float* __restrict__ w1, float* __restrict__ f1) {
    __shared__ float Xs[64][65];
    __shared__ float Ws[64*64];
    int t = blockIdx.y;
    int n0 = blockIdx.x*64;
    int tid = threadIdx.x;
    for (int e = tid; e < 4096; e += 256) {
        int n = e >> 6, k = e & 63;
        int gn = n0 + n;
        Xs[n][k] = (gn < NN) ? h1[(size_t)gn*192 + (k>>5)*96 + t*32 + (k&31)] : 0.f;
        Ws[e] = w1[t*4096 + e];
    }
    __syncthreads();
    int ix = tid & 15, iy = tid >> 4;
    float acc[4][4] = {};
    #pragma unroll 8
    for (int k = 0; k < 64; ++k) {
        float4 wv = *(const float4*)&Ws[k*64 + iy*4];
        #pragma unroll
        for (int p = 0; p < 4; ++p) {
            float x = Xs[ix*4+p][k];
            acc[p][0] += x*wv.x; acc[p][1] += x*wv.y; acc[p][2] += x*wv.z; acc[p][3] += x*wv.w;
        }
    }
    int h = iy >> 3, dd = (iy & 7)*4;  // out col = h*32 + dd
    #pragma unroll
    for (int p = 0; p < 4; ++p) {
        int gn = n0 + ix*4 + p;
        if (gn < NN)
            *(float4*)&f1[(size_t)gn*192 + h*96 + t*32 + dd] = make_float4(acc[p][0],acc[p][1],acc[p][2],acc[p][3]);
    }
}

// ---- layer2 feat + residual (GEMM-tiled per slot t, W = [w2_t | resw2]) ----
__global__ __launch_bounds__(256) void k_f2t(const float* __restrict__ h2,
        const float* __restrict__ w2, const float* __restrict__ rw,
        float* __restrict__ f2, float* __restrict__ rst2) {
    __shared__ float Xs[64][65];
    __shared__ float Ws[64*64];
    int t = blockIdx.y;
    int n0 = blockIdx.x*64;
    int tid = threadIdx.x;
    for (int e = tid; e < 4096; e += 256) {
        int n = e >> 6, k = e & 63;
        int gn = n0 + n;
        Xs[n][k] = (gn < NN) ? h2[(size_t)gn*192 + (k>>5)*96 + t*32 + (k&31)] : 0.f;
        int c = e & 63;
        Ws[e] = (c < 32) ? w2[t*2048 + n*32 + c] : rw[n*32 + (c-32)];  // n==e>>6==k index
    }
    __syncthreads();
    int ix = tid & 15, iy = tid >> 4;
    float acc[4][4] = {};
    #pragma unroll 8
    for (int k = 0; k < 64; ++k) {
        float4 wv = *(const float4*)&Ws[k*64 + iy*4];
        #pragma unroll
        for (int p = 0; p < 4; ++p) {
            float x = Xs[ix*4+p][k];
            acc[p][0] += x*wv.x; acc[p][1] += x*wv.y; acc[p][2] += x*wv.z; acc[p][3] += x*wv.w;
        }
    }
    #pragma unroll
    for (int p = 0; p < 4; ++p) {
        int gn = n0 + ix*4 + p;
        if (gn < NN) {
            float4 v = make_float4(acc[p][0],acc[p][1],acc[p][2],acc[p][3]);
            if (iy < 8) *(float4*)&f2[(size_t)gn*96 + t*32 + iy*4] = v;
            else        *(float4*)&rst2[(size_t)gn*96 + t*32 + (iy-8)*4] = v;
        }
    }
}

// ---- CSR build ----
__global__ void k_deg(const int* __restrict__ dst, int* __restrict__ deg) {
    int e = blockIdx.x*256 + threadIdx.x;
    if (e < EE) atomicAdd(&deg[dst[e]], 1);
}

__global__ __launch_bounds__(1024) void k_scan(const int* __restrict__ deg, int* __restrict__ rowptr) {
    __shared__ int sbase;
    __shared__ int wsum[16];
    int tid = threadIdx.x;
    if (tid == 0) sbase = 0;
    __syncthreads();
    for (int c0 = 0; c0 < NN; c0 += 1024) {
        int i = c0 + tid;
        int v = (i < NN) ? deg[i] : 0;
        int x = v;
        for (int d = 1; d < 64; d <<= 1) { int y = __shfl_up(x, d, 64); if ((tid & 63) >= d) x += y; }
        if ((tid & 63) == 63) wsum[tid >> 6] = x;
        __syncthreads();
        if (tid < 16) { int w = wsum[tid];
            for (int d = 1; d < 16; d <<= 1) { int y = __shfl_up(w, d, 64); if (tid >= d) w += y; }
            wsum[tid] = w; }
        __syncthreads();
        int woff = (tid >> 6) == 0 ? 0 : wsum[(tid >> 6) - 1];
        int incl = x + woff;
        if (i < NN) rowptr[i] = sbase + incl - v;
        __syncthreads();
        if (tid == 1023) sbase += incl;
        __syncthreads();
    }
    if (tid == 0) rowptr[NN] = sbase;
}

__global__ void k_fill(const int* __restrict__ dst, const int* __restrict__ rowptr,
                       int* __restrict__ cursor, int* __restrict__ eidx) {
    int e = blockIdx.x*256 + threadIdx.x;
    if (e >= EE) return;
    int d = dst[e];
    int pos = atomicAdd(&cursor[d], 1);
    eidx[rowptr[d] + pos] = e;
}

// ---- pair bucketing by relation: wave-ballot aggregated ----
__global__ __launch_bounds__(256) void k_bcnt(const int* __restrict__ mid, int* __restrict__ cnt) {
    __shared__ int h[RR];
    int tid = threadIdx.x, lane = tid & 63;
    if (tid < RR) h[tid] = 0;
    __syncthreads();
    int b = blockIdx.x*256 + tid;
    int r = (b < BB) ? mid[b] : -1;
    #pragma unroll
    for (int rr = 0; rr < RR; ++rr) {
        unsigned long long m = __ballot(r == rr);
        if (lane == 0 && m) atomicAdd(&h[rr], (int)__popcll(m));
    }
    __syncthreads();
    if (tid < RR && h[tid]) atomicAdd(&cnt[tid], h[tid]);
}

__global__ void k_bscan(const int* __restrict__ cnt, int* __restrict__ base) {
    base[0] = 0;
    for (int r = 0; r < RR; ++r) base[r+1] = base[r] + (((cnt[r] + 63) >> 6) << 6);
}

__global__ __launch_bounds__(256) void k_bfill(const int* __restrict__ mid, const int* __restrict__ base,
                        int* __restrict__ gcur, int* __restrict__ perm) {
    __shared__ int wcnt[4][RR];
    __shared__ int wbase[4][RR];
    __shared__ int bbase[RR];
    int tid = threadIdx.x, w = tid >> 6, lane = tid & 63;
    int b = blockIdx.x*256 + tid;
    int r = (b < BB) ? mid[b] : -1;
    int myrank = 0;
    #pragma unroll
    for (int rr = 0; rr < RR; ++rr) {
        unsigned long long m = __ballot(r == rr);
        if (r == rr) myrank = (int)__popcll(m & ((1ull << lane) - 1ull));
        if (lane == 0) wcnt[w][rr] = (int)__popcll(m);
    }
    __syncthreads();
    if (tid < RR) {
        int s = 0;
        #pragma unroll
        for (int ww = 0; ww < 4; ++ww) { wbase[ww][tid] = s; s += wcnt[ww][tid]; }
        bbase[tid] = s ? atomicAdd(&gcur[tid], s) : 0;
    }
    __syncthreads();
    if (r >= 0) perm[base[r] + bbase[r] + wbase[w][r] + myrank] = b;
}

// ---- edge logit table [R,H] ----
__global__ void k_tab(const float* __restrict__ eemb, const float* __restrict__ fcw,
                      const float* __restrict__ fcb, const float* __restrict__ ae,
                      int H, float* __restrict__ tab) {
    int r = blockIdx.x / H, h = blockIdx.x % H, d = threadIdx.x;
    float acc = fcb[h*64+d];
    const float* er = eemb + r*64;
    #pragma unroll
    for (int k = 0; k < 64; ++k) acc += er[k] * fcw[k*(H*64) + h*64 + d];
    float v = acc * ae[h*64+d];
    for (int off = 32; off; off >>= 1) v += __shfl_xor(v, off, 64);
    if (d == 0) tab[r*H+h] = v;
}

// ---- fused per-node softmax + gather-aggregate ----
template<int MODE, int H>
__global__ __launch_bounds__(192) void k_aggr(
        const int* __restrict__ rowptr, const int* __restrict__ eidx,
        const int* __restrict__ src, const int* __restrict__ et,
        const float* __restrict__ el, const float* __restrict__ er,
        const float* __restrict__ tab, const float* __restrict__ f,
        const float* __restrict__ resat, float* __restrict__ store0,
        const float* __restrict__ resid, float* __restrict__ outp) {
    __shared__ float s_a[128][2];
    __shared__ int s_src[128];
    __shared__ int s_ts[128];
    int n = blockIdx.x, tid = threadIdx.x;
    int e0 = rowptr[n];
    int deg = rowptr[n+1] - e0;
    float m0 = -1e30f, m1 = -1e30f, sum0 = 0.f, sum1 = 0.f;
    float er0 = 0.f, er1 = 0.f;
    if (tid < 64) {
        er0 = er[n*H];
        if (H == 2) er1 = er[n*H+1];
        for (int s2 = tid; s2 < deg; s2 += 64) {
            int e = eidx[e0+s2]; int sN = src[e]; int rr = et[e];
            float x0 = lrelu(el[sN*H] + er0 + tab[rr*H]);
            m0 = fmaxf(m0, x0);
            if (H == 2) { float x1 = lrelu(el[sN*H+1] + er1 + tab[rr*H+1]); m1 = fmaxf(m1, x1); }
        }
        for (int off = 32; off; off >>= 1) {
            m0 = fmaxf(m0, __shfl_xor(m0, off, 64));
            if (H == 2) m1 = fmaxf(m1, __shfl_xor(m1, off, 64));
        }
        for (int s2 = tid; s2 < deg; s2 += 64) {
            int e = eidx[e0+s2]; int sN = src[e]; int rr = et[e];
            float x0 = lrelu(el[sN*H] + er0 + tab[rr*H]);
            sum0 += __expf(x0 - m0);
            if (H == 2) { float x1 = lrelu(el[sN*H+1] + er1 + tab[rr*H+1]); sum1 += __expf(x1 - m1); }
        }
        for (int off = 32; off; off >>= 1) {
            sum0 += __shfl_xor(sum0, off, 64);
            if (H == 2) sum1 += __shfl_xor(sum1, off, 64);
        }
    }
    float acc = 0.f;
    int h = tid / 96, km = tid - h*96, t = km >> 5, d = km & 31;
    for (int c0 = 0; c0 < deg; c0 += 128) {
        int cl = min(128, deg - c0);
        if (tid < 64) {
            for (int s2 = tid; s2 < cl; s2 += 64) {
                int e = eidx[e0+c0+s2]; int sN = src[e]; int rr = et[e];
                float x0 = lrelu(el[sN*H] + er0 + tab[rr*H]);
                float a0 = __expf(x0 - m0) / (sum0 + 1e-9f);
                if (MODE == 1) a0 = a0*0.95f + resat[e*2]*0.05f;
                if (MODE == 0) store0[e*2] = a0;
                s_a[s2][0] = a0;
                if (H == 2) {
                    float x1 = lrelu(el[sN*H+1] + er1 + tab[rr*H+1]);
                    float a1 = __expf(x1 - m1) / (sum1 + 1e-9f);
                    if (MODE == 1) a1 = a1*0.95f + resat[e*2+1]*0.05f;
                    if (MODE == 0) store0[e*2+1] = a1;
                    s_a[s2][1] = a1;
                }
                s_src[s2] = sN;
                if (MODE == 0) s_ts[s2] = sN / NPER;
            }
        }
        __syncthreads();
        if (MODE == 0) {
            for (int s2 = 0; s2 < cl; ++s2)
                if (s_ts[s2] == t) acc += s_a[s2][h] * f[(size_t)s_src[s2]*64 + h*32 + d];
        } else if (MODE == 1) {
            for (int s2 = 0; s2 < cl; ++s2)
                acc += s_a[s2][h] * f[(size_t)s_src[s2]*192 + tid];
        } else {
            if (tid < 96)
                for (int s2 = 0; s2 < cl; ++s2)
                    acc += s_a[s2][0] * f[(size_t)s_src[s2]*96 + tid];
        }
        __syncthreads();
    }
    if (MODE == 0) outp[(size_t)n*192 + tid] = acc;
    else if (MODE == 1) outp[(size_t)n*192 + tid] = resid[(size_t)n*192 + tid] + acc;
    else if (tid < 96) outp[(size_t)n*96 + tid] = resid[(size_t)n*96 + tid] + acc;
}

// ---- el/er for layer1 ----
__global__ void k_el1(const float* __restrict__ f1, const float* __restrict__ al,
                      const float* __restrict__ ar, float* __restrict__ el, float* __restrict__ er) {
    int gid = blockIdx.x*256 + threadIdx.x;
    int n = gid >> 6, l = gid & 63;
    if (n >= NN) return;
    const float* b = f1 + (size_t)n*192;
    float v0 = b[l], v1 = b[l+64], v2 = b[l+128];
    float pe0 = v0*al[l],     pr0 = v0*ar[l];
    float pe1 = v2*al[l+128], pr1 = v2*ar[l+128];
    float me = v1*al[l+64], mr = v1*ar[l+64];
    if (l < 32) { pe0 += me; pr0 += mr; } else { pe1 += me; pr1 += mr; }
    for (int off = 32; off; off >>= 1) {
        pe0 += __shfl_xor(pe0, off, 64); pr0 += __shfl_xor(pr0, off, 64);
        pe1 += __shfl_xor(pe1, off, 64); pr1 += __shfl_xor(pr1, off, 64);
    }
    if (l == 0) { el[n*2] = pe0; el[n*2+1] = pe1; er[n*2] = pr0; er[n*2+1] = pr1; }
}

// ---- el/er for layer2 ----
__global__ void k_el2(const float* __restrict__ f2, const float* __restrict__ al,
                      const float* __restrict__ ar, float* __restrict__ el, float* __restrict__ er) {
    int gid = blockIdx.x*256 + threadIdx.x;
    int n = gid >> 6, l = gid & 63;
    if (n >= NN) return;
    const float* b = f2 + (size_t)n*96;
    float v0 = b[l];
    float pe = v0*al[l], pr = v0*ar[l];
    if (l < 32) { float v1 = b[64+l]; pe += v1*al[64+l]; pr += v1*ar[64+l]; }
    for (int off = 32; off; off >>= 1) { pe += __shfl_xor(pe, off, 64); pr += __shfl_xor(pr, off, 64); }
    if (l == 0) { el[n] = pe; er[n] = pr; }
}

// ---- finalize layer 0/1 ----
__global__ __launch_bounds__(192) void k_final01(float* __restrict__ rst, const float* __restrict__ bias,
                          float* __restrict__ z, int zcol) {
    __shared__ float xs[2][96];
    __shared__ float sn[2];
    int tid = threadIdx.x;
    int ln = tid / 96, k = tid - ln*96;
    int n = blockIdx.x*2 + ln;
    if (tid < 2) sn[tid] = 0.f;
    float v0 = eluf(rst[(size_t)n*192 + k]      + bias[k]);
    float v1 = eluf(rst[(size_t)n*192 + 96 + k] + bias[96+k]);
    rst[(size_t)n*192 + k] = v0;
    rst[(size_t)n*192 + 96 + k] = v1;
    float x = 0.5f*(v0+v1);
    xs[ln][k] = x;
    __syncthreads();
    atomicAdd(&sn[ln], x*x);
    __syncthreads();
    float nr = fmaxf(sqrtf(sn[ln]), 1e-12f);
    if (k < 32) z[(size_t)n*128 + zcol + k] = (xs[ln][k] + xs[ln][32+k] + xs[ln][64+k]) / (3.f*nr);
}

// ---- finalize layer 2 ----
__global__ __launch_bounds__(192) void k_final2(const float* __restrict__ rst2, const float* __restrict__ bias,
                         float* __restrict__ z) {
    __shared__ float xs[2][96];
    __shared__ float sn[2];
    int tid = threadIdx.x;
    int ln = tid / 96, k = tid - ln*96;
    int n = blockIdx.x*2 + ln;
    if (tid < 2) sn[tid] = 0.f;
    float x = rst2[(size_t)n*96 + k] + bias[k];
    xs[ln][k] = x;
    __syncthreads();
    atomicAdd(&sn[ln], x*x);
    __syncthreads();
    float nr = fmaxf(sqrtf(sn[ln]), 1e-12f);
    if (k < 32) z[(size_t)n*128 + 96 + k] = (xs[ln][k] + xs[ln][32+k] + xs[ln][64+k]) / (3.f*nr);
}

// ---- DistMult: bucketed pair tiles, register-tiled; 64 pairs/block ----
__global__ __launch_bounds__(256) void k_dm2(const float* __restrict__ z, const float* __restrict__ W,
                       const int* __restrict__ left, const int* __restrict__ right,
                       const int* __restrict__ mid, const int* __restrict__ perm,
                       float* __restrict__ out) {
    __shared__ float le_s[64][129];
    __shared__ float w_s[32][128];
    __shared__ int s_b[64], s_l[64], s_r[64];
    int tid = threadIdx.x;
    if (tid < 64) {
        int b = perm[blockIdx.x*64 + tid];
        s_b[tid] = b;
        s_l[tid] = (b >= 0) ? left[b]  : 0;
        s_r[tid] = (b >= 0) ? right[b] : 0;
    }
    __syncthreads();
    if (s_b[0] < 0) return;
    int r = mid[s_b[0]];
    for (int i = tid; i < 8192; i += 256) {
        int p = i >> 7, c = i & 127;
        le_s[p][c] = z[(size_t)s_l[p]*128 + c];
    }
    const float* Wp = W + (size_t)r*16384;
    int tx = tid & 15, ty = tid >> 4;
    float acc[4][8];
    #pragma unroll
    for (int pp = 0; pp < 4; ++pp)
        #pragma unroll
        for (int i2 = 0; i2 < 8; ++i2) acc[pp][i2] = 0.f;
    for (int k0 = 0; k0 < 128; k0 += 32) {
        __syncthreads();
        for (int i = tid; i < 4096; i += 256) {
            int kk = i >> 7, c = i & 127;
            w_s[kk][c] = Wp[(size_t)(k0+kk)*128 + c];
        }
        __syncthreads();
        #pragma unroll 4
        for (int kk = 0; kk < 32; ++kk) {
            float wv[8], lv[4];
            #pragma unroll
            for (int i2 = 0; i2 < 8; ++i2) wv[i2] = w_s[kk][tx + 16*i2];
            #pragma unroll
            for (int pp = 0; pp < 4; ++pp) lv[pp] = le_s[ty*4+pp][k0+kk];
            #pragma unroll
            for (int pp = 0; pp < 4; ++pp)
                #pragma unroll
                for (int i2 = 0; i2 < 8; ++i2) acc[pp][i2] += lv[pp]*wv[i2];
        }
    }
    #pragma unroll
    for (int pp = 0; pp < 4; ++pp) {
        int p = ty*4 + pp;
        const float* zr = z + (size_t)s_r[p]*128;
        float part = 0.f;
        #pragma unroll
        for (int i2 = 0; i2 < 8; ++i2) part += acc[pp][i2] * zr[tx + 16*i2];
        for (int off = 8; off; off >>= 1) part += __shfl_xor(part, off, 64);
        if (tx == 0 && s_b[p] >= 0) out[s_b[p]] = part;
    }
}

extern "C" void kernel_launch(void* const* d_in, const int* in_sizes, int n_in,
                              void* d_out, int out_size, void* d_ws, size_t ws_size,
                              hipStream_t stream) {
    const float* feats = (const float*)d_in[0];
    const float* fc_w  = (const float*)d_in[1];
    const float* fc_b  = (const float*)d_in[2];
    const float* w0    = (const float*)d_in[3];
    const float* al0   = (const float*)d_in[4];
    const float* ar0   = (const float*)d_in[5];
    const float* b0    = (const float*)d_in[6];
    const float* eemb0 = (const float*)d_in[7];
    const float* fce_w0= (const float*)d_in[8];
    const float* fce_b0= (const float*)d_in[9];
    const float* ae0   = (const float*)d_in[10];
    const float* w1    = (const float*)d_in[11];
    const float* al1   = (const float*)d_in[12];
    const float* ar1   = (const float*)d_in[13];
    const float* b1    = (const float*)d_in[14];
    const float* eemb1 = (const float*)d_in[15];
    const float* fce_w1= (const float*)d_in[16];
    const float* fce_b1= (const float*)d_in[17];
    const float* ae1   = (const float*)d_in[18];
    const float* w2    = (const float*)d_in[19];
    const float* al2   = (const float*)d_in[20];
    const float* ar2   = (const float*)d_in[21];
    const float* b2    = (const float*)d_in[22];
    const float* eemb2 = (const float*)d_in[23];
    const float* fce_w2= (const float*)d_in[24];
    const float* fce_b2= (const float*)d_in[25];
    const float* ae2   = (const float*)d_in[26];
    const float* resw2 = (const float*)d_in[27];
    const float* Wdm   = (const float*)d_in[28];
    const int* src   = (const int*)d_in[29];
    const int* dst   = (const int*)d_in[30];
    const int* etype = (const int*)d_in[31];
    const int* left  = (const int*)d_in[32];
    const int* right = (const int*)d_in[33];
    const int* mid   = (const int*)d_in[34];
    float* out = (float*)d_out;

    char* ws = (char*)d_ws;
    size_t off = 0;
    auto alloc = [&](size_t bytes) -> void* {
        void* p = ws + off;
        off = (off + bytes + 255) & ~(size_t)255;
        return p;
    };
    float* z    = (float*)alloc((size_t)NN*128*4);
    float* fbuf = (float*)alloc((size_t)NN*192*4);
    float* r0   = (float*)alloc((size_t)NN*192*4);
    float* r1   = (float*)alloc((size_t)NN*192*4);
    float* r2   = (float*)alloc((size_t)NN*96*4);
    float* el   = (float*)alloc((size_t)NN*2*4);
    float* er   = (float*)alloc((size_t)NN*2*4);
    float* a0b  = (float*)alloc((size_t)EE*2*4);
    int* rowptr = (int*)alloc((size_t)(NN+1)*4);
    int* eidx   = (int*)alloc((size_t)EE*4);
    int* degc   = (int*)alloc((size_t)NN*4);
    int* perm   = (int*)alloc((size_t)NT*64*4);
    int* bcnt   = (int*)alloc(8*4);
    int* bbase  = (int*)alloc(8*4);
    int* bcur   = (int*)alloc(8*4);
    float* cwb  = (float*)alloc((size_t)T_*4096*4);
    float* cbb  = (float*)alloc((size_t)T_*64*4);
    float* tab0 = (float*)alloc(256);
    float* tab1 = (float*)alloc(256);
    float* tab2 = (float*)alloc(256);

    // ---- CSR build (by dst) ----
    hipMemsetAsync(degc, 0, (size_t)NN*4, stream);
    k_deg<<<dim3(EE/256), dim3(256), 0, stream>>>(dst, degc);
    k_scan<<<dim3(1), dim3(1024), 0, stream>>>(degc, rowptr);
    hipMemsetAsync(degc, 0, (size_t)NN*4, stream);
    k_fill<<<dim3(EE/256), dim3(256), 0, stream>>>(dst, rowptr, degc, eidx);

    // ---- pair buckets by relation ----
    hipMemsetAsync(bcnt, 0, 8*4, stream);
    hipMemsetAsync(bcur, 0, 8*4, stream);
    hipMemsetAsync(perm, 0xFF, (size_t)NT*64*4, stream);
    k_bcnt<<<dim3((BB+255)/256), dim3(256), 0, stream>>>(mid, bcnt);
    k_bscan<<<dim3(1), dim3(1), 0, stream>>>(bcnt, bbase);
    k_bfill<<<dim3((BB+255)/256), dim3(256), 0, stream>>>(mid, bbase, bcur, perm);

    // ---- stage 0 ----
    k_combine<<<dim3(T_), dim3(256), 0, stream>>>(fc_w, fc_b, w0, cwb, cbb);
    k_ntz<<<dim3(TILEST, T_), dim3(256), 0, stream>>>(feats, fc_w, fc_b, z);
    k_tab<<<dim3(RR*2), dim3(64), 0, stream>>>(eemb0, fce_w0, fce_b0, ae0, 2, tab0);
    k_tab<<<dim3(RR*2), dim3(64), 0, stream>>>(eemb1, fce_w1, fce_b1, ae1, 2, tab1);
    k_tab<<<dim3(RR*1), dim3(64), 0, stream>>>(eemb2, fce_w2, fce_b2, ae2, 1, tab2);

    // ---- layer 0 ----
    k_f0t<<<dim3(TILEST, T_), dim3(256), 0, stream>>>(feats, cwb, cbb, al0, ar0, fbuf, el, er);
    k_aggr<0,2><<<dim3(NN), dim3(192), 0, stream>>>(rowptr, eidx, src, etype, el, er, tab0,
                                                    fbuf, nullptr, a0b, nullptr, r0);
    k_final01<<<dim3(NN/2), dim3(192), 0, stream>>>(r0, b0, z, 32);   // r0 -> h1

    // ---- layer 1 ----
    k_f1t<<<dim3(TILESN, T_), dim3(256), 0, stream>>>(r0, w1, fbuf);
    k_el1<<<dim3((NN*64)/256), dim3(256), 0, stream>>>(fbuf, al1, ar1, el, er);
    k_aggr<1,2><<<dim3(NN), dim3(192), 0, stream>>>(rowptr, eidx, src, etype, el, er, tab1,
                                                    fbuf, a0b, nullptr, r0, r1);
    k_final01<<<dim3(NN/2), dim3(192), 0, stream>>>(r1, b1, z, 64);   // r1 -> h2

    // ---- layer 2 ----
    k_f2t<<<dim3(TILESN, T_), dim3(256), 0, stream>>>(r1, w2, resw2, fbuf, r2);
    k_el2<<<dim3((NN*64)/256), dim3(256), 0, stream>>>(fbuf, al2, ar2, el, er);
    k_aggr<2,1><<<dim3(NN), dim3(192), 0, stream>>>(rowptr, eidx, src, etype, el, er, tab2,
                                                    fbuf, nullptr, nullptr, r2, r2);
    k_final2<<<dim3(NN/2), dim3(192), 0, stream>>>(r2, b2, z);

    // ---- DistMult ----
    k_dm2<<<dim3(NT), dim3(256), 0, stream>>>(z, Wdm, left, right, mid, perm, out);
}

// Round 5
// 959.199 us; speedup vs baseline: 3.3798x; 1.1855x over previous
//
#include <hip/hip_runtime.h>

#define T_ 3
#define NPER 20000
#define NN 60000
#define EE 480000
#define BB 200000
#define RR 5
#define NT 3130    // BB/64 + RR  (padded pair tiles)
#define TILESN 938 // ceil(NN/64)
#define TILEST 313 // ceil(NPER/64)

__device__ inline float lrelu(float x){ return x > 0.f ? x : 0.2f*x; }
__device__ inline float eluf(float x){ return x > 0.f ? x : (__expf(x) - 1.f); }
__device__ inline void fma4(float4& a, float s, const float4 v){ a.x+=s*v.x; a.y+=s*v.y; a.z+=s*v.z; a.w+=s*v.w; }

// ---- combine input-fc with layer0 weights: cw[t]=fcw[t]@w0[t] [64x64], cb[t]=fcb[t]@w0[t] ----
__global__ __launch_bounds__(256) void k_combine(const float* __restrict__ fcw,
        const float* __restrict__ fcb, const float* __restrict__ w0,
        float* __restrict__ cw, float* __restrict__ cb) {
    __shared__ float A[64*32];   // fcw_t [k][m]
    __shared__ float Bm[32*64];  // w0_t  [m][o]
    int t = blockIdx.x, tid = threadIdx.x;
    for (int e = tid; e < 2048; e += 256) { A[e] = fcw[t*2048 + e]; Bm[e] = w0[t*2048 + e]; }
    __syncthreads();
    for (int e = tid; e < 4096; e += 256) {
        int k = e >> 6, o = e & 63;
        float acc = 0.f;
        #pragma unroll
        for (int m = 0; m < 32; ++m) acc += A[k*32+m] * Bm[m*64+o];
        cw[t*4096 + e] = acc;
    }
    if (tid < 64) {
        float acc = 0.f;
        #pragma unroll
        for (int m = 0; m < 32; ++m) acc += fcb[t*32+m] * Bm[m*64+tid];
        cb[t*64 + tid] = acc;
    }
}

// ---- fused input-fc + emb0: z[:,0:32] = (feats@fcw_t+fcb_t) / (3*||.||) ----
__global__ __launch_bounds__(256) void k_ntz(const float* __restrict__ feats,
        const float* __restrict__ fcw, const float* __restrict__ fcb,
        float* __restrict__ z) {
    __shared__ float Xs[64][65];
    __shared__ float Ws[64*32];
    __shared__ float nrS[64];
    int ty = blockIdx.y;
    int n0 = ty*NPER + blockIdx.x*64;
    int nmax = (ty+1)*NPER;
    int tid = threadIdx.x;
    for (int e = tid; e < 4096; e += 256) {
        int n = e >> 6, k = e & 63;
        int gn = n0 + n;
        Xs[n][k] = (gn < nmax) ? feats[(size_t)gn*64 + k] : 0.f;
    }
    for (int e = tid; e < 2048; e += 256) Ws[e] = fcw[ty*2048 + e];
    __syncthreads();
    int ix = tid & 15, iy = tid >> 4;  // nodes 4ix.., cols 2iy..
    float acc[4][2] = {};
    #pragma unroll 8
    for (int k = 0; k < 64; ++k) {
        float wa = Ws[k*32 + 2*iy], wb = Ws[k*32 + 2*iy + 1];
        #pragma unroll
        for (int p = 0; p < 4; ++p) {
            float x = Xs[ix*4+p][k];
            acc[p][0] += x*wa; acc[p][1] += x*wb;
        }
    }
    float ba = fcb[ty*32 + 2*iy], bb = fcb[ty*32 + 2*iy + 1];
    __syncthreads();
    #pragma unroll
    for (int p = 0; p < 4; ++p) {
        acc[p][0] += ba; acc[p][1] += bb;
        Xs[ix*4+p][2*iy] = acc[p][0]; Xs[ix*4+p][2*iy+1] = acc[p][1];
    }
    __syncthreads();
    if (tid < 64) {
        float ss = 0.f;
        #pragma unroll
        for (int c = 0; c < 32; ++c) { float v = Xs[tid][c]; ss += v*v; }
        nrS[tid] = 3.f * fmaxf(sqrtf(ss), 1e-12f);
    }
    __syncthreads();
    #pragma unroll
    for (int p = 0; p < 4; ++p) {
        int gn = n0 + ix*4 + p;
        if (gn < nmax) {
            float inv = 1.f / nrS[ix*4+p];
            z[(size_t)gn*128 + 2*iy]   = acc[p][0]*inv;
            z[(size_t)gn*128 + 2*iy+1] = acc[p][1]*inv;
        }
    }
}

// ---- layer0 feat (GEMM-tiled): f0 = feats@cw_t + cb_t, + el/er epilogue ----
__global__ __launch_bounds__(256) void k_f0t(const float* __restrict__ feats,
        const float* __restrict__ cw, const float* __restrict__ cb,
        const float* __restrict__ al, const float* __restrict__ ar,
        float* __restrict__ f0, float* __restrict__ el, float* __restrict__ er) {
    __shared__ float Xs[64][65];
    __shared__ float Ws[64*64];
    __shared__ float avec[2][32], rvec[2][32];
    int ty = blockIdx.y;
    int n0 = ty*NPER + blockIdx.x*64;
    int nmax = (ty+1)*NPER;
    int tid = threadIdx.x;
    for (int e = tid; e < 4096; e += 256) {
        int n = e >> 6, k = e & 63;
        int gn = n0 + n;
        Xs[n][k] = (gn < nmax) ? feats[(size_t)gn*64 + k] : 0.f;
        Ws[e] = cw[ty*4096 + e];
    }
    if (tid < 64) {
        avec[tid>>5][tid&31] = al[(tid>>5)*96 + ty*32 + (tid&31)];
        rvec[tid>>5][tid&31] = ar[(tid>>5)*96 + ty*32 + (tid&31)];
    }
    __syncthreads();
    int ix = tid & 15, iy = tid >> 4;  // nodes 4ix.., cols 4iy..
    float acc[4][4] = {};
    #pragma unroll 8
    for (int k = 0; k < 64; ++k) {
        float4 wv = *(const float4*)&Ws[k*64 + iy*4];
        #pragma unroll
        for (int p = 0; p < 4; ++p) {
            float x = Xs[ix*4+p][k];
            acc[p][0] += x*wv.x; acc[p][1] += x*wv.y; acc[p][2] += x*wv.z; acc[p][3] += x*wv.w;
        }
    }
    float b0v = cb[ty*64 + iy*4], b1v = cb[ty*64 + iy*4+1], b2v = cb[ty*64 + iy*4+2], b3v = cb[ty*64 + iy*4+3];
    __syncthreads();   // done with Xs; reuse as F tile
    #pragma unroll
    for (int p = 0; p < 4; ++p) {
        acc[p][0] += b0v; acc[p][1] += b1v; acc[p][2] += b2v; acc[p][3] += b3v;
        Xs[ix*4+p][iy*4]   = acc[p][0];
        Xs[ix*4+p][iy*4+1] = acc[p][1];
        Xs[ix*4+p][iy*4+2] = acc[p][2];
        Xs[ix*4+p][iy*4+3] = acc[p][3];
    }
    #pragma unroll
    for (int p = 0; p < 4; ++p) {
        int gn = n0 + ix*4 + p;
        if (gn < nmax)
            *(float4*)&f0[(size_t)gn*64 + iy*4] = make_float4(acc[p][0],acc[p][1],acc[p][2],acc[p][3]);
    }
    __syncthreads();
    if (tid < 128) {
        int n = tid >> 1, h = tid & 1;
        int gn = n0 + n;
        float pe = 0.f, pr = 0.f;
        #pragma unroll
        for (int d = 0; d < 32; ++d) {
            float v = Xs[n][h*32+d];
            pe += v*avec[h][d]; pr += v*rvec[h][d];
        }
        if (gn < nmax) { el[gn*2+h] = pe; er[gn*2+h] = pr; }
    }
}

// ---- layer1 feat (GEMM-tiled per slot t) ----
__global__ __launch_bounds__(256) void k_f1t(const float* __restrict__ h1,
        const float* __restrict__ w1, float* __restrict__ f1) {
    __shared__ float Xs[64][65];
    __shared__ float Ws[64*64];
    int t = blockIdx.y;
    int n0 = blockIdx.x*64;
    int tid = threadIdx.x;
    for (int e = tid; e < 4096; e += 256) {
        int n = e >> 6, k = e & 63;
        int gn = n0 + n;
        Xs[n][k] = (gn < NN) ? h1[(size_t)gn*192 + (k>>5)*96 + t*32 + (k&31)] : 0.f;
        Ws[e] = w1[t*4096 + e];
    }
    __syncthreads();
    int ix = tid & 15, iy = tid >> 4;
    float acc[4][4] = {};
    #pragma unroll 8
    for (int k = 0; k < 64; ++k) {
        float4 wv = *(const float4*)&Ws[k*64 + iy*4];
        #pragma unroll
        for (int p = 0; p < 4; ++p) {
            float x = Xs[ix*4+p][k];
            acc[p][0] += x*wv.x; acc[p][1] += x*wv.y; acc[p][2] += x*wv.z; acc[p][3] += x*wv.w;
        }
    }
    int h = iy >> 3, dd = (iy & 7)*4;  // out col = h*32 + dd
    #pragma unroll
    for (int p = 0; p < 4; ++p) {
        int gn = n0 + ix*4 + p;
        if (gn < NN)
            *(float4*)&f1[(size_t)gn*192 + h*96 + t*32 + dd] = make_float4(acc[p][0],acc[p][1],acc[p][2],acc[p][3]);
    }
}

// ---- layer2 feat + residual (GEMM-tiled per slot t, W = [w2_t | resw2]) ----
__global__ __launch_bounds__(256) void k_f2t(const float* __restrict__ h2,
        const float* __restrict__ w2, const float* __restrict__ rw,
        float* __restrict__ f2, float* __restrict__ rst2) {
    __shared__ float Xs[64][65];
    __shared__ float Ws[64*64];
    int t = blockIdx.y;
    int n0 = blockIdx.x*64;
    int tid = threadIdx.x;
    for (int e = tid; e < 4096; e += 256) {
        int n = e >> 6, k = e & 63;
        int gn = n0 + n;
        Xs[n][k] = (gn < NN) ? h2[(size_t)gn*192 + (k>>5)*96 + t*32 + (k&31)] : 0.f;
        int c = e & 63;
        Ws[e] = (c < 32) ? w2[t*2048 + n*32 + c] : rw[n*32 + (c-32)];
    }
    __syncthreads();
    int ix = tid & 15, iy = tid >> 4;
    float acc[4][4] = {};
    #pragma unroll 8
    for (int k = 0; k < 64; ++k) {
        float4 wv = *(const float4*)&Ws[k*64 + iy*4];
        #pragma unroll
        for (int p = 0; p < 4; ++p) {
            float x = Xs[ix*4+p][k];
            acc[p][0] += x*wv.x; acc[p][1] += x*wv.y; acc[p][2] += x*wv.z; acc[p][3] += x*wv.w;
        }
    }
    #pragma unroll
    for (int p = 0; p < 4; ++p) {
        int gn = n0 + ix*4 + p;
        if (gn < NN) {
            float4 v = make_float4(acc[p][0],acc[p][1],acc[p][2],acc[p][3]);
            if (iy < 8) *(float4*)&f2[(size_t)gn*96 + t*32 + iy*4] = v;
            else        *(float4*)&rst2[(size_t)gn*96 + t*32 + (iy-8)*4] = v;
        }
    }
}

// ---- CSR build ----
__global__ void k_deg(const int* __restrict__ dst, int* __restrict__ deg) {
    int e = blockIdx.x*256 + threadIdx.x;
    if (e < EE) atomicAdd(&deg[dst[e]], 1);
}

__global__ __launch_bounds__(1024) void k_scan(const int* __restrict__ deg, int* __restrict__ rowptr) {
    __shared__ int sbase;
    __shared__ int wsum[16];
    int tid = threadIdx.x;
    if (tid == 0) sbase = 0;
    __syncthreads();
    for (int c0 = 0; c0 < NN; c0 += 1024) {
        int i = c0 + tid;
        int v = (i < NN) ? deg[i] : 0;
        int x = v;
        for (int d = 1; d < 64; d <<= 1) { int y = __shfl_up(x, d, 64); if ((tid & 63) >= d) x += y; }
        if ((tid & 63) == 63) wsum[tid >> 6] = x;
        __syncthreads();
        if (tid < 16) { int w = wsum[tid];
            for (int d = 1; d < 16; d <<= 1) { int y = __shfl_up(w, d, 64); if (tid >= d) w += y; }
            wsum[tid] = w; }
        __syncthreads();
        int woff = (tid >> 6) == 0 ? 0 : wsum[(tid >> 6) - 1];
        int incl = x + woff;
        if (i < NN) rowptr[i] = sbase + incl - v;
        __syncthreads();
        if (tid == 1023) sbase += incl;
        __syncthreads();
    }
    if (tid == 0) rowptr[NN] = sbase;
}

__global__ void k_fill(const int* __restrict__ dst, const int* __restrict__ rowptr,
                       int* __restrict__ cursor, int* __restrict__ eidx) {
    int e = blockIdx.x*256 + threadIdx.x;
    if (e >= EE) return;
    int d = dst[e];
    int pos = atomicAdd(&cursor[d], 1);
    eidx[rowptr[d] + pos] = e;
}

// ---- pair bucketing by relation: wave-ballot aggregated ----
__global__ __launch_bounds__(256) void k_bcnt(const int* __restrict__ mid, int* __restrict__ cnt) {
    __shared__ int h[RR];
    int tid = threadIdx.x, lane = tid & 63;
    if (tid < RR) h[tid] = 0;
    __syncthreads();
    int b = blockIdx.x*256 + tid;
    int r = (b < BB) ? mid[b] : -1;
    #pragma unroll
    for (int rr = 0; rr < RR; ++rr) {
        unsigned long long m = __ballot(r == rr);
        if (lane == 0 && m) atomicAdd(&h[rr], (int)__popcll(m));
    }
    __syncthreads();
    if (tid < RR && h[tid]) atomicAdd(&cnt[tid], h[tid]);
}

__global__ void k_bscan(const int* __restrict__ cnt, int* __restrict__ base) {
    base[0] = 0;
    for (int r = 0; r < RR; ++r) base[r+1] = base[r] + (((cnt[r] + 63) >> 6) << 6);
}

__global__ __launch_bounds__(256) void k_bfill(const int* __restrict__ mid, const int* __restrict__ base,
                        int* __restrict__ gcur, int* __restrict__ perm) {
    __shared__ int wcnt[4][RR];
    __shared__ int wbase[4][RR];
    __shared__ int bbase[RR];
    int tid = threadIdx.x, w = tid >> 6, lane = tid & 63;
    int b = blockIdx.x*256 + tid;
    int r = (b < BB) ? mid[b] : -1;
    int myrank = 0;
    #pragma unroll
    for (int rr = 0; rr < RR; ++rr) {
        unsigned long long m = __ballot(r == rr);
        if (r == rr) myrank = (int)__popcll(m & ((1ull << lane) - 1ull));
        if (lane == 0) wcnt[w][rr] = (int)__popcll(m);
    }
    __syncthreads();
    if (tid < RR) {
        int s = 0;
        #pragma unroll
        for (int ww = 0; ww < 4; ++ww) { wbase[ww][tid] = s; s += wcnt[ww][tid]; }
        bbase[tid] = s ? atomicAdd(&gcur[tid], s) : 0;
    }
    __syncthreads();
    if (r >= 0) perm[base[r] + bbase[r] + wbase[w][r] + myrank] = b;
}

// ---- edge logit table [R,H] ----
__global__ void k_tab(const float* __restrict__ eemb, const float* __restrict__ fcw,
                      const float* __restrict__ fcb, const float* __restrict__ ae,
                      int H, float* __restrict__ tab) {
    int r = blockIdx.x / H, h = blockIdx.x % H, d = threadIdx.x;
    float acc = fcb[h*64+d];
    const float* er = eemb + r*64;
    #pragma unroll
    for (int k = 0; k < 64; ++k) acc += er[k] * fcw[k*(H*64) + h*64 + d];
    float v = acc * ae[h*64+d];
    for (int off = 32; off; off >>= 1) v += __shfl_xor(v, off, 64);
    if (d == 0) tab[r*H+h] = v;
}

// ---- fused per-node softmax + float4/ILP gather-aggregate + finalize epilogue ----
// MODE 0: H=2, f=[N,64] slot-compact; store a->store0; out=elu(acc+bias) -> r0; z[:,32:64]
// MODE 1: H=2, f=[N,192]; mix resat; out=elu(acc+resid+bias) -> r1; z[:,64:96]
// MODE 2: H=1, f=[N,96]; no out store; val=acc+resid+bias; z[:,96:128]
template<int MODE, int H>
__global__ __launch_bounds__(192) void k_aggr(
        const int* __restrict__ rowptr, const int* __restrict__ eidx,
        const int* __restrict__ src, const int* __restrict__ et,
        const float* __restrict__ el, const float* __restrict__ er,
        const float* __restrict__ tab, const float* __restrict__ f,
        const float* __restrict__ resat, float* __restrict__ store0,
        const float* __restrict__ resid, const float* __restrict__ bias,
        float* __restrict__ outp, float* __restrict__ z, int zc) {
    constexpr int COLS  = (MODE==0) ? 64 : (MODE==1) ? 192 : 96;
    constexpr int LANES = COLS/4;
    constexpr int G     = 192/LANES;          // edges in flight
    constexpr int RCOLS = (MODE==0) ? 192 : COLS;
    __shared__ float s_a[128][2];
    __shared__ int s_src[128];
    __shared__ int s_ts[128];
    __shared__ __align__(16) float red[G][RCOLS];
    __shared__ float hs[192];
    __shared__ float xs[96];
    __shared__ float part[2];
    int n = blockIdx.x, tid = threadIdx.x;
    int e0 = rowptr[n];
    int deg = rowptr[n+1] - e0;
    float m0 = -1e30f, m1 = -1e30f, sum0 = 0.f, sum1 = 0.f;
    float er0 = 0.f, er1 = 0.f;
    if (tid < 64) {
        er0 = er[n*H];
        if (H == 2) er1 = er[n*H+1];
        for (int s2 = tid; s2 < deg; s2 += 64) {
            int e = eidx[e0+s2]; int sN = src[e]; int rr = et[e];
            float x0 = lrelu(el[sN*H] + er0 + tab[rr*H]);
            m0 = fmaxf(m0, x0);
            if (H == 2) { float x1 = lrelu(el[sN*H+1] + er1 + tab[rr*H+1]); m1 = fmaxf(m1, x1); }
        }
        for (int off = 32; off; off >>= 1) {
            m0 = fmaxf(m0, __shfl_xor(m0, off, 64));
            if (H == 2) m1 = fmaxf(m1, __shfl_xor(m1, off, 64));
        }
        for (int s2 = tid; s2 < deg; s2 += 64) {
            int e = eidx[e0+s2]; int sN = src[e]; int rr = et[e];
            float x0 = lrelu(el[sN*H] + er0 + tab[rr*H]);
            sum0 += __expf(x0 - m0);
            if (H == 2) { float x1 = lrelu(el[sN*H+1] + er1 + tab[rr*H+1]); sum1 += __expf(x1 - m1); }
        }
        for (int off = 32; off; off >>= 1) {
            sum0 += __shfl_xor(sum0, off, 64);
            if (H == 2) sum1 += __shfl_xor(sum1, off, 64);
        }
    }
    // register accumulators (float4 per thread; MODE0 has one per slot)
    float4 acc0 = {0,0,0,0}, acc1 = {0,0,0,0}, acc2 = {0,0,0,0};
    int g = tid / LANES;
    int col = (tid - g*LANES)*4;
    int hcol = (MODE==0) ? (col >> 5) : (MODE==1) ? (col / 96) : 0;
    for (int c0 = 0; c0 < deg; c0 += 128) {
        int cl = min(128, deg - c0);
        if (tid < 64) {
            for (int s2 = tid; s2 < cl; s2 += 64) {
                int e = eidx[e0+c0+s2]; int sN = src[e]; int rr = et[e];
                float x0 = lrelu(el[sN*H] + er0 + tab[rr*H]);
                float a0 = __expf(x0 - m0) / (sum0 + 1e-9f);
                if (MODE == 1) a0 = a0*0.95f + resat[e*2]*0.05f;
                if (MODE == 0) store0[e*2] = a0;
                s_a[s2][0] = a0;
                if (H == 2) {
                    float x1 = lrelu(el[sN*H+1] + er1 + tab[rr*H+1]);
                    float a1 = __expf(x1 - m1) / (sum1 + 1e-9f);
                    if (MODE == 1) a1 = a1*0.95f + resat[e*2+1]*0.05f;
                    if (MODE == 0) store0[e*2+1] = a1;
                    s_a[s2][1] = a1;
                }
                s_src[s2] = sN;
                if (MODE == 0) s_ts[s2] = sN / NPER;
            }
        }
        __syncthreads();
        for (int s2 = g; s2 < cl; s2 += G) {
            int sN = s_src[s2];
            float a = s_a[s2][hcol];
            float4 v = *(const float4*)&f[(size_t)sN*COLS + col];
            if (MODE == 0) {
                int ts = s_ts[s2];
                fma4(acc0, (ts==0)?a:0.f, v);
                fma4(acc1, (ts==1)?a:0.f, v);
                fma4(acc2, (ts==2)?a:0.f, v);
            } else {
                fma4(acc0, a, v);
            }
        }
        __syncthreads();
    }
    // cross-group reduction
    if (MODE == 0) {
        *(float4*)&red[g][col]       = acc0;
        *(float4*)&red[g][64 + col]  = acc1;
        *(float4*)&red[g][128 + col] = acc2;
    } else {
        *(float4*)&red[g][col] = acc0;
    }
    __syncthreads();
    constexpr int FC = (MODE==2) ? 96 : 192;
    if (tid < FC) {
        int rc;
        if (MODE == 0) { int hh = tid/96, km = tid - hh*96, t = km>>5, d = km&31; rc = t*64 + hh*32 + d; }
        else rc = tid;
        float val = 0.f;
        #pragma unroll
        for (int gg = 0; gg < G; ++gg) val += red[gg][rc];
        if (MODE == 0) val = eluf(val + bias[tid]);
        if (MODE == 1) val = eluf(val + resid[(size_t)n*192 + tid] + bias[tid]);
        if (MODE == 2) val = val + resid[(size_t)n*96 + tid] + bias[tid];
        if (MODE < 2) outp[(size_t)n*192 + tid] = val;
        hs[tid] = val;
    }
    __syncthreads();
    float xx = 0.f;
    if (tid < 96) {
        float x = (MODE==2) ? hs[tid] : 0.5f*(hs[tid] + hs[96+tid]);
        xs[tid] = x;
        xx = x*x;
    }
    float s = xx;
    for (int off = 32; off; off >>= 1) s += __shfl_xor(s, off, 64);
    if ((tid & 63) == 0 && tid < 128) part[tid>>6] = s;
    __syncthreads();
    if (tid < 32) {
        float nr = 3.f * fmaxf(sqrtf(part[0] + part[1]), 1e-12f);
        z[(size_t)n*128 + zc + tid] = (xs[tid] + xs[32+tid] + xs[64+tid]) / nr;
    }
}

// ---- el/er for layer1 ----
__global__ void k_el1(const float* __restrict__ f1, const float* __restrict__ al,
                      const float* __restrict__ ar, float* __restrict__ el, float* __restrict__ er) {
    int gid = blockIdx.x*256 + threadIdx.x;
    int n = gid >> 6, l = gid & 63;
    if (n >= NN) return;
    const float* b = f1 + (size_t)n*192;
    float v0 = b[l], v1 = b[l+64], v2 = b[l+128];
    float pe0 = v0*al[l],     pr0 = v0*ar[l];
    float pe1 = v2*al[l+128], pr1 = v2*ar[l+128];
    float me = v1*al[l+64], mr = v1*ar[l+64];
    if (l < 32) { pe0 += me; pr0 += mr; } else { pe1 += me; pr1 += mr; }
    for (int off = 32; off; off >>= 1) {
        pe0 += __shfl_xor(pe0, off, 64); pr0 += __shfl_xor(pr0, off, 64);
        pe1 += __shfl_xor(pe1, off, 64); pr1 += __shfl_xor(pr1, off, 64);
    }
    if (l == 0) { el[n*2] = pe0; el[n*2+1] = pe1; er[n*2] = pr0; er[n*2+1] = pr1; }
}

// ---- el/er for layer2 ----
__global__ void k_el2(const float* __restrict__ f2, const float* __restrict__ al,
                      const float* __restrict__ ar, float* __restrict__ el, float* __restrict__ er) {
    int gid = blockIdx.x*256 + threadIdx.x;
    int n = gid >> 6, l = gid & 63;
    if (n >= NN) return;
    const float* b = f2 + (size_t)n*96;
    float v0 = b[l];
    float pe = v0*al[l], pr = v0*ar[l];
    if (l < 32) { float v1 = b[64+l]; pe += v1*al[64+l]; pr += v1*ar[64+l]; }
    for (int off = 32; off; off >>= 1) { pe += __shfl_xor(pe, off, 64); pr += __shfl_xor(pr, off, 64); }
    if (l == 0) { el[n] = pe; er[n] = pr; }
}

// ---- DistMult: bucketed pair tiles, register-tiled; 64 pairs/block ----
__global__ __launch_bounds__(256) void k_dm2(const float* __restrict__ z, const float* __restrict__ W,
                       const int* __restrict__ left, const int* __restrict__ right,
                       const int* __restrict__ mid, const int* __restrict__ perm,
                       float* __restrict__ out) {
    __shared__ float le_s[64][129];
    __shared__ float w_s[32][128];
    __shared__ int s_b[64], s_l[64], s_r[64];
    int tid = threadIdx.x;
    if (tid < 64) {
        int b = perm[blockIdx.x*64 + tid];
        s_b[tid] = b;
        s_l[tid] = (b >= 0) ? left[b]  : 0;
        s_r[tid] = (b >= 0) ? right[b] : 0;
    }
    __syncthreads();
    if (s_b[0] < 0) return;
    int r = mid[s_b[0]];
    for (int i = tid; i < 8192; i += 256) {
        int p = i >> 7, c = i & 127;
        le_s[p][c] = z[(size_t)s_l[p]*128 + c];
    }
    const float* Wp = W + (size_t)r*16384;
    int tx = tid & 15, ty = tid >> 4;
    float acc[4][8];
    #pragma unroll
    for (int pp = 0; pp < 4; ++pp)
        #pragma unroll
        for (int i2 = 0; i2 < 8; ++i2) acc[pp][i2] = 0.f;
    for (int k0 = 0; k0 < 128; k0 += 32) {
        __syncthreads();
        for (int i = tid; i < 4096; i += 256) {
            int kk = i >> 7, c = i & 127;
            w_s[kk][c] = Wp[(size_t)(k0+kk)*128 + c];
        }
        __syncthreads();
        #pragma unroll 4
        for (int kk = 0; kk < 32; ++kk) {
            float wv[8], lv[4];
            #pragma unroll
            for (int i2 = 0; i2 < 8; ++i2) wv[i2] = w_s[kk][tx + 16*i2];
            #pragma unroll
            for (int pp = 0; pp < 4; ++pp) lv[pp] = le_s[ty*4+pp][k0+kk];
            #pragma unroll
            for (int pp = 0; pp < 4; ++pp)
                #pragma unroll
                for (int i2 = 0; i2 < 8; ++i2) acc[pp][i2] += lv[pp]*wv[i2];
        }
    }
    #pragma unroll
    for (int pp = 0; pp < 4; ++pp) {
        int p = ty*4 + pp;
        const float* zr = z + (size_t)s_r[p]*128;
        float part = 0.f;
        #pragma unroll
        for (int i2 = 0; i2 < 8; ++i2) part += acc[pp][i2] * zr[tx + 16*i2];
        for (int off = 8; off; off >>= 1) part += __shfl_xor(part, off, 64);
        if (tx == 0 && s_b[p] >= 0) out[s_b[p]] = part;
    }
}

extern "C" void kernel_launch(void* const* d_in, const int* in_sizes, int n_in,
                              void* d_out, int out_size, void* d_ws, size_t ws_size,
                              hipStream_t stream) {
    const float* feats = (const float*)d_in[0];
    const float* fc_w  = (const float*)d_in[1];
    const float* fc_b  = (const float*)d_in[2];
    const float* w0    = (const float*)d_in[3];
    const float* al0   = (const float*)d_in[4];
    const float* ar0   = (const float*)d_in[5];
    const float* b0    = (const float*)d_in[6];
    const float* eemb0 = (const float*)d_in[7];
    const float* fce_w0= (const float*)d_in[8];
    const float* fce_b0= (const float*)d_in[9];
    const float* ae0   = (const float*)d_in[10];
    const float* w1    = (const float*)d_in[11];
    const float* al1   = (const float*)d_in[12];
    const float* ar1   = (const float*)d_in[13];
    const float* b1    = (const float*)d_in[14];
    const float* eemb1 = (const float*)d_in[15];
    const float* fce_w1= (const float*)d_in[16];
    const float* fce_b1= (const float*)d_in[17];
    const float* ae1   = (const float*)d_in[18];
    const float* w2    = (const float*)d_in[19];
    const float* al2   = (const float*)d_in[20];
    const float* ar2   = (const float*)d_in[21];
    const float* b2    = (const float*)d_in[22];
    const float* eemb2 = (const float*)d_in[23];
    const float* fce_w2= (const float*)d_in[24];
    const float* fce_b2= (const float*)d_in[25];
    const float* ae2   = (const float*)d_in[26];
    const float* resw2 = (const float*)d_in[27];
    const float* Wdm   = (const float*)d_in[28];
    const int* src   = (const int*)d_in[29];
    const int* dst   = (const int*)d_in[30];
    const int* etype = (const int*)d_in[31];
    const int* left  = (const int*)d_in[32];
    const int* right = (const int*)d_in[33];
    const int* mid   = (const int*)d_in[34];
    float* out = (float*)d_out;

    char* ws = (char*)d_ws;
    size_t off = 0;
    auto alloc = [&](size_t bytes) -> void* {
        void* p = ws + off;
        off = (off + bytes + 255) & ~(size_t)255;
        return p;
    };
    float* z    = (float*)alloc((size_t)NN*128*4);
    float* fbuf = (float*)alloc((size_t)NN*192*4);
    float* r0   = (float*)alloc((size_t)NN*192*4);
    float* r1   = (float*)alloc((size_t)NN*192*4);
    float* r2   = (float*)alloc((size_t)NN*96*4);
    float* el   = (float*)alloc((size_t)NN*2*4);
    float* er   = (float*)alloc((size_t)NN*2*4);
    float* a0b  = (float*)alloc((size_t)EE*2*4);
    int* rowptr = (int*)alloc((size_t)(NN+1)*4);
    int* eidx   = (int*)alloc((size_t)EE*4);
    int* degc   = (int*)alloc((size_t)NN*4);
    int* perm   = (int*)alloc((size_t)NT*64*4);
    int* bcnt   = (int*)alloc(8*4);
    int* bbase  = (int*)alloc(8*4);
    int* bcur   = (int*)alloc(8*4);
    float* cwb  = (float*)alloc((size_t)T_*4096*4);
    float* cbb  = (float*)alloc((size_t)T_*64*4);
    float* tab0 = (float*)alloc(256);
    float* tab1 = (float*)alloc(256);
    float* tab2 = (float*)alloc(256);

    // ---- CSR build (by dst) ----
    hipMemsetAsync(degc, 0, (size_t)NN*4, stream);
    k_deg<<<dim3(EE/256), dim3(256), 0, stream>>>(dst, degc);
    k_scan<<<dim3(1), dim3(1024), 0, stream>>>(degc, rowptr);
    hipMemsetAsync(degc, 0, (size_t)NN*4, stream);
    k_fill<<<dim3(EE/256), dim3(256), 0, stream>>>(dst, rowptr, degc, eidx);

    // ---- pair buckets by relation ----
    hipMemsetAsync(bcnt, 0, 8*4, stream);
    hipMemsetAsync(bcur, 0, 8*4, stream);
    hipMemsetAsync(perm, 0xFF, (size_t)NT*64*4, stream);
    k_bcnt<<<dim3((BB+255)/256), dim3(256), 0, stream>>>(mid, bcnt);
    k_bscan<<<dim3(1), dim3(1), 0, stream>>>(bcnt, bbase);
    k_bfill<<<dim3((BB+255)/256), dim3(256), 0, stream>>>(mid, bbase, bcur, perm);

    // ---- stage 0 ----
    k_combine<<<dim3(T_), dim3(256), 0, stream>>>(fc_w, fc_b, w0, cwb, cbb);
    k_ntz<<<dim3(TILEST, T_), dim3(256), 0, stream>>>(feats, fc_w, fc_b, z);
    k_tab<<<dim3(RR*2), dim3(64), 0, stream>>>(eemb0, fce_w0, fce_b0, ae0, 2, tab0);
    k_tab<<<dim3(RR*2), dim3(64), 0, stream>>>(eemb1, fce_w1, fce_b1, ae1, 2, tab1);
    k_tab<<<dim3(RR*1), dim3(64), 0, stream>>>(eemb2, fce_w2, fce_b2, ae2, 1, tab2);

    // ---- layer 0 ----
    k_f0t<<<dim3(TILEST, T_), dim3(256), 0, stream>>>(feats, cwb, cbb, al0, ar0, fbuf, el, er);
    k_aggr<0,2><<<dim3(NN), dim3(192), 0, stream>>>(rowptr, eidx, src, etype, el, er, tab0,
                                                    fbuf, nullptr, a0b, nullptr, b0, r0, z, 32);

    // ---- layer 1 ----
    k_f1t<<<dim3(TILESN, T_), dim3(256), 0, stream>>>(r0, w1, fbuf);
    k_el1<<<dim3((NN*64)/256), dim3(256), 0, stream>>>(fbuf, al1, ar1, el, er);
    k_aggr<1,2><<<dim3(NN), dim3(192), 0, stream>>>(rowptr, eidx, src, etype, el, er, tab1,
                                                    fbuf, a0b, nullptr, r0, b1, r1, z, 64);

    // ---- layer 2 ----
    k_f2t<<<dim3(TILESN, T_), dim3(256), 0, stream>>>(r1, w2, resw2, fbuf, r2);
    k_el2<<<dim3((NN*64)/256), dim3(256), 0, stream>>>(fbuf, al2, ar2, el, er);
    k_aggr<2,1><<<dim3(NN), dim3(192), 0, stream>>>(rowptr, eidx, src, etype, el, er, tab2,
                                                    fbuf, nullptr, nullptr, r2, b2, nullptr, z, 96);

    // ---- DistMult ----
    k_dm2<<<dim3(NT), dim3(256), 0, stream>>>(z, Wdm, left, right, mid, perm, out);
}